// Round 3
// baseline (747.618 us; speedup 1.0000x reference)
//
#include <hip/hip_runtime.h>
#include <stdint.h>

// Problem constants (Attention_39556648796173)
// Inputs: float32 buffers (per reference dtypes). Output: float32.
// Compute core: bf16 MFMA (comparison tolerance is bf16-scaled: 2% of max).
#define TTOK  8192
#define DIMM  2048
#define NH    16
#define NKV   8
#define HD    128
#define SEQ   1024
#define BATCH 8
#define BLKSZ 16

typedef unsigned short u16;
typedef __attribute__((ext_vector_type(8))) short bfrag;   // 8 x bf16 (4 VGPRs)
typedef __attribute__((ext_vector_type(4))) float f32x4;   // MFMA accumulator

__device__ __forceinline__ float bf2f(u16 u) {
  unsigned int v = ((unsigned int)u) << 16;
  float f; __builtin_memcpy(&f, &v, 4); return f;
}
__device__ __forceinline__ u16 f2bf(float f) {
  unsigned int v; __builtin_memcpy(&v, &f, 4);
  v = v + 0x7FFFu + ((v >> 16) & 1u);   // RNE
  return (u16)(v >> 16);
}

// async global->LDS, 16B per lane; LDS dest = wave-uniform base + lane*16
__device__ __forceinline__ void gll16(const void* g, void* l) {
  __builtin_amdgcn_global_load_lds(
      (__attribute__((address_space(1))) void*)(g),
      (__attribute__((address_space(3))) void*)(l), 16, 0, 0);
}
// full drain (vmcnt=0, expcnt=0, lgkmcnt=0) + compiler memory fence
__device__ __forceinline__ void hard_fence() {
  asm volatile("" ::: "memory");
  __builtin_amdgcn_s_waitcnt(0);
  asm volatile("" ::: "memory");
}

// ---------------------------------------------------------------------------
// fp32 -> bf16 bulk convert (n multiple of 2048); 8 elems/thread
// ---------------------------------------------------------------------------
__global__ __launch_bounds__(256) void f32_to_bf16(const float* __restrict__ in,
                                                   u16* __restrict__ out, size_t n) {
  size_t i = ((size_t)blockIdx.x * 256 + threadIdx.x) * 8;
  if (i >= n) return;
  float4 a = *(const float4*)(in + i);
  float4 b = *(const float4*)(in + i + 4);
  union { u16 o[8]; uint4 v; } u;
  u.o[0] = f2bf(a.x); u.o[1] = f2bf(a.y); u.o[2] = f2bf(a.z); u.o[3] = f2bf(a.w);
  u.o[4] = f2bf(b.x); u.o[5] = f2bf(b.y); u.o[6] = f2bf(b.z); u.o[7] = f2bf(b.w);
  *(uint4*)(out + i) = u.v;
}

// ---------------------------------------------------------------------------
// Tiled transpose + fp32->bf16: out[n][k] = bf16(in[k][n]), K,N multiples of 64
// ---------------------------------------------------------------------------
__global__ __launch_bounds__(256) void ktranspose_f(const float* __restrict__ in,
                                                    u16* __restrict__ out, int K, int N) {
  __shared__ __align__(16) u16 tile[64 * 65];
  int n0 = blockIdx.x * 64, k0 = blockIdx.y * 64;
  int tx = threadIdx.x & 63, ty = threadIdx.x >> 6;
  for (int r = 0; r < 16; ++r) {
    int kk = r * 4 + ty;
    tile[kk * 65 + tx] = f2bf(in[(size_t)(k0 + kk) * N + n0 + tx]);
  }
  __syncthreads();
  for (int r = 0; r < 16; ++r) {
    int nn = r * 4 + ty;
    out[(size_t)(n0 + nn) * K + k0 + tx] = tile[tx * 65 + nn];
  }
}

// ---------------------------------------------------------------------------
// m97-style GEMM: C[M,N] = A[M,K] @ B, with B given transposed (Bt[N,K]).
// 128x128 tile, BK=32, 4 waves (2x2 of 64x64), mfma 16x16x32 bf16.
// ---------------------------------------------------------------------------
template <typename OutT>
__global__ __launch_bounds__(256) void gemm_bt(const u16* __restrict__ A,
                                               const u16* __restrict__ Bt,
                                               OutT* __restrict__ C,
                                               int M, int N, int K) {
  __shared__ __align__(16) u16 As[128 * 32];
  __shared__ __align__(16) u16 Bs[128 * 32];
  int tid = threadIdx.x;
  int wave = tid >> 6, lane = tid & 63, quad = lane >> 4, l15 = lane & 15;
  int m0 = blockIdx.y * 128, n0 = blockIdx.x * 128;
  int wm = (wave >> 1) * 64, wn = (wave & 1) * 64;

  f32x4 acc[4][4];
  for (int i = 0; i < 4; ++i)
    for (int j = 0; j < 4; ++j) acc[i][j] = (f32x4){0.f, 0.f, 0.f, 0.f};

  int g0 = wave * 64 + lane;            // granules 0..255
  int g1 = 256 + wave * 64 + lane;      // granules 256..511
  const u16* Arow0 = A + (size_t)(m0 + (g0 >> 2)) * K + (g0 & 3) * 8;
  const u16* Arow1 = A + (size_t)(m0 + (g1 >> 2)) * K + (g1 & 3) * 8;
  const u16* Brow0 = Bt + (size_t)(n0 + (g0 >> 2)) * K + (g0 & 3) * 8;
  const u16* Brow1 = Bt + (size_t)(n0 + (g1 >> 2)) * K + (g1 & 3) * 8;
  char* AsB = (char*)As;
  char* BsB = (char*)Bs;
  int lds0 = wave * 1024, lds1 = 4096 + wave * 1024;  // wave-uniform bases

  for (int k0 = 0; k0 < K; k0 += 32) {
    __syncthreads();                 // all waves done reading previous tile
    asm volatile("" ::: "memory");
    gll16(Arow0 + k0, AsB + lds0);
    gll16(Arow1 + k0, AsB + lds1);
    gll16(Brow0 + k0, BsB + lds0);
    gll16(Brow1 + k0, BsB + lds1);
    hard_fence();                    // own DMA fully landed in LDS
    __syncthreads();                 // everyone's DMA landed

    bfrag af[4], bfv[4];
    for (int im = 0; im < 4; ++im) {
      int m = wm + im * 16 + l15;
      af[im] = *(const bfrag*)(AsB + m * 64 + quad * 16);
    }
    for (int jn = 0; jn < 4; ++jn) {
      int n = wn + jn * 16 + l15;
      bfv[jn] = *(const bfrag*)(BsB + n * 64 + quad * 16);
    }
    for (int im = 0; im < 4; ++im)
      for (int jn = 0; jn < 4; ++jn)
        acc[im][jn] = __builtin_amdgcn_mfma_f32_16x16x32_bf16(af[im], bfv[jn], acc[im][jn], 0, 0, 0);
  }

  // C/D layout: col = lane&15, row = quad*4 + reg  (m89/m91 verified)
  for (int im = 0; im < 4; ++im)
    for (int jn = 0; jn < 4; ++jn)
      for (int r = 0; r < 4; ++r) {
        int row = m0 + wm + im * 16 + quad * 4 + r;
        int col = n0 + wn + jn * 16 + l15;
        if constexpr (__is_same(OutT, float))
          C[(size_t)row * N + col] = acc[im][jn][r];
        else
          C[(size_t)row * N + col] = f2bf(acc[im][jn][r]);
      }
}

// ---------------------------------------------------------------------------
// RoPE (interleaved pairs) + scatter into Q[b][h][s][d] (token order) and
// paged K/V caches [blk][kvh][off][d] honoring block_tables.
// ---------------------------------------------------------------------------
__global__ __launch_bounds__(256) void rope_scatter(const u16* __restrict__ xqkv,
                                                    const int* __restrict__ positions,
                                                    const int* __restrict__ btab,
                                                    u16* __restrict__ qb,
                                                    u16* __restrict__ kb,
                                                    u16* __restrict__ vbuf) {
  int t = blockIdx.x;
  int tid = threadIdx.x;
  int b = t >> 10, srow = t & 1023;
  int pos = positions[t];
  int blk = btab[b * (SEQ / BLKSZ) + (pos >> 4)];
  int off = pos & (BLKSZ - 1);
  int c0 = tid * 16;

  struct __align__(16) { uint4 a, bq; } vv, oo;
  const u16* src = xqkv + (size_t)t * 4096 + c0;
  vv.a  = *(const uint4*)src;
  vv.bq = *(const uint4*)(src + 8);
  const u16* v = (const u16*)&vv;
  u16* o = (u16*)&oo;

  if (c0 < 3072) {  // Q or K section: apply RoPE on (even,odd) pairs
    int dbase = c0 & 127;
    float fpos = (float)pos;
    for (int j = 0; j < 8; ++j) {
      int i = (dbase >> 1) + j;                       // freq index 0..63
      float inv = exp2f(-(float)i * (13.287712379549449f / 64.0f)); // 10000^(-i/64)
      float ang = fpos * inv;
      float sn, cs;
      sincosf(ang, &sn, &cs);
      float fr = bf2f(v[2 * j]), fi = bf2f(v[2 * j + 1]);
      o[2 * j]     = f2bf(fr * cs - fi * sn);
      o[2 * j + 1] = f2bf(fr * sn + fi * cs);
    }
  } else {
    for (int j = 0; j < 16; ++j) o[j] = v[j];
  }

  u16* dst;
  if (c0 < 2048) {
    int head = c0 >> 7, d0 = c0 & 127;
    dst = qb + (((size_t)(b * NH + head)) * SEQ + srow) * HD + d0;
  } else if (c0 < 3072) {
    int cc = c0 - 2048;
    int kvh = cc >> 7, d0 = cc & 127;
    dst = kb + (((size_t)(blk * NKV + kvh) * BLKSZ + off)) * HD + d0;
  } else {
    int cc = c0 - 3072;
    int kvh = cc >> 7, d0 = cc & 127;
    dst = vbuf + (((size_t)(blk * NKV + kvh) * BLKSZ + off)) * HD + d0;
  }
  *(uint4*)dst = oo.a;
  *(uint4*)(dst + 8) = oo.bq;
}

// ---------------------------------------------------------------------------
// Flash attention v2, paged cache — KVT=64 + T14 async-stage version.
// (Resubmission of round-2 source: the round-2 bench died to an infra
// failure — "container failed twice" — with no compile/correctness signal.
// Kernel re-audited: no divergent barriers, no OOB, prefetch regs are
// self-produced/self-consumed. Unchanged for a clean A/B vs round 1.)
//
// Round-1 post-mortem: balanced pairing (v1) left dur EXACTLY unchanged at
// 199us (v0 198.7) with all throughput counters low (Mfma 7%, HBM 12%,
// VALU 29%). Both versions share 18432 block-iterations with identical
// fixed per-iteration cost: staging load latency exposed between two full
// __syncthreads drains. => the kernel is bound by per-iteration serial
// latency, not by any pipe and not by imbalance.
//
// This version halves the iteration count (KV tile 32 -> 64 tokens, 9216
// block-iterations) and hides the staging-load latency (T14): next tile's
// global loads are issued right after the compute barrier, fly during the
// ~1000-cycle compute phase, and are drained by the NEXT iteration's first
// __syncthreads. Per-iteration exposed cost is now write+2 barriers+compute.
//
// Layout: 8 waves x 16 q-rows; block owns q-tile pair (y, 7-y) => 18
// KV-tile iterations per block, exactly uniform. Softmax runs in log2
// domain (scale folded into exp args). LDS strides padded so all reads
// are <=2-way bank-aliased (free, m136). LDS 54272 B, VGPR capped at 128
// (__launch_bounds__(512,4)) => 2 blocks/CU resident.
// ---------------------------------------------------------------------------
#define KVT 64
#define KS_STRIDE 272   // bytes per K token row (128*2 + 16 pad)
#define VT_STRIDE 144   // bytes per V d row (64*2 + 16 pad)
#define PS_STRIDE 144   // bytes per P q row (64*2 + 16 pad)

__global__ __launch_bounds__(512, 4) void attn_kernel(const u16* __restrict__ Q,
                                                      const u16* __restrict__ Kc,
                                                      const u16* __restrict__ Vc,
                                                      const int* __restrict__ positions,
                                                      const int* __restrict__ btab,
                                                      u16* __restrict__ O) {
  __shared__ __align__(16) u16 Ks[KVT * (KS_STRIDE / 2)];     // [tok][d] padded, 17408 B
  __shared__ __align__(16) u16 Vt[HD * (VT_STRIDE / 2)];      // [d][tok] padded, 18432 B
  __shared__ __align__(16) u16 Ps[8 * 16 * (PS_STRIDE / 2)];  // [wave][q][tok], 18432 B
  const float SM_SCALE = 0.08838834764831845f; // 1/sqrt(128)
  const float LOG2E    = 1.4426950408889634f;
  const float C1       = SM_SCALE * LOG2E;     // score -> log2-domain
  const float NEGBIG   = -30000.0f;
  const float NEGINIT  = -1e30f;
  const float DEFER2   = 8.0f * LOG2E;         // T13 threshold in log2 domain

  int tid = threadIdx.x;
  int wave = tid >> 6, lane = tid & 63, quad = lane >> 4, l15 = lane & 15;
  int bid = blockIdx.x;
  int bh = bid >> 2, pr = bid & 3;             // pair index 0..3
  int b = bh >> 4, h = bh & 15, kvh = h >> 1;
  const int* btrow = btab + b * (SEQ / BLKSZ);

  char* KsB = (char*)Ks;
  char* VtB = (char*)Vt;
  char* myPsB = (char*)Ps + wave * 16 * PS_STRIDE;

  // K staging decode: 1024 granules of 16B (64 tok x 16 dg), 2 per thread
  int tokA = tid >> 4;          // rows 0..31
  int tokB = tokA + 32;         // rows 32..63
  int dgK  = tid & 15;
  // V staging decode: 2 tokens x 8 d per thread (transpose in regs)
  int tokV = (tid & 31) * 2;    // even token 0..62 (odd = +1, same cache blk)
  int vd0  = (tid >> 5) * 8;    // 0..120

  uint4 kr0, kr1, vr0, vr1;     // T14 prefetch registers

  // load tile starting at token index kti (multiple of 64) into regs
  auto load_tile = [&](int kti) {
    int i0 = kti >> 4;
    int b0 = btrow[i0], b1 = btrow[i0 + 1], b2 = btrow[i0 + 2], b3 = btrow[i0 + 3];
    const u16* KA = Kc + ((size_t)(((tokA < 16) ? b0 : b1) * NKV + kvh) * BLKSZ + (tokA & 15)) * HD + dgK * 8;
    const u16* KB = Kc + ((size_t)(((tokB < 48) ? b2 : b3) * NKV + kvh) * BLKSZ + (tokB & 15)) * HD + dgK * 8;
    kr0 = *(const uint4*)KA;
    kr1 = *(const uint4*)KB;
    int bv = (tokV < 16) ? b0 : (tokV < 32) ? b1 : (tokV < 48) ? b2 : b3;
    const u16* VA = Vc + ((size_t)(bv * NKV + kvh) * BLKSZ + (tokV & 15)) * HD + vd0;
    vr0 = *(const uint4*)VA;
    vr1 = *(const uint4*)(VA + HD);
  };

  for (int pass = 0; pass < 2; ++pass) {
    int yt = pass ? (7 - pr) : pr;             // q-tile of this pass
    int q0 = yt * 128;
    int qw = q0 + wave * 16;                   // this wave's 16 rows

    const u16* Qbase = Q + ((size_t)bh * SEQ + qw) * HD;

    // Q fragments (A-layout: m=lane&15, k=quad*8+j): 4 k-blocks
    bfrag aq[4];
#pragma unroll
    for (int kb2 = 0; kb2 < 4; ++kb2)
      aq[kb2] = *(const bfrag*)(Qbase + (size_t)l15 * HD + kb2 * 32 + quad * 8);

    int qpos[4];
#pragma unroll
    for (int r = 0; r < 4; ++r)
      qpos[r] = positions[(size_t)b * SEQ + qw + quad * 4 + r];

    f32x4 oa[8];
#pragma unroll
    for (int jd = 0; jd < 8; ++jd) oa[jd] = (f32x4){0.f, 0.f, 0.f, 0.f};
    float m2_i[4], l_i[4];
#pragma unroll
    for (int r = 0; r < 4; ++r) { m2_i[r] = NEGINIT; l_i[r] = 0.f; }

    int kend = q0 + 128;
    load_tile(0);                              // pass prologue prefetch

    for (int kt = 0; kt < kend; kt += KVT) {
      __syncthreads();     // #1: prev tile's LDS reads done; drains vmcnt ->
                           //     prefetched regs landed (hidden under compute)
      // regs -> LDS
      *(uint4*)(KsB + tokA * KS_STRIDE + dgK * 16) = kr0;
      *(uint4*)(KsB + tokB * KS_STRIDE + dgK * 16) = kr1;
      {
        const u16* p0 = (const u16*)&vr0;
        const u16* p1 = (const u16*)&vr1;
#pragma unroll
        for (int jj = 0; jj < 8; ++jj) {
          unsigned int val = (unsigned int)p0[jj] | ((unsigned int)p1[jj] << 16);
          *(unsigned int*)(VtB + (vd0 + jj) * VT_STRIDE + tokV * 2) = val;
        }
      }
      __syncthreads();     // #2: LDS tile ready (nothing else pending)

      // T14: issue next tile's loads now; they fly during compute and are
      // drained by the next iteration's barrier #1.
      if (kt + KVT < kend) load_tile(kt + KVT);

      if (kt <= qw + 15) {                     // wave-uniform skip
        // S = Q K^T  (16 q x 64 tok)
        f32x4 sa[4];
#pragma unroll
        for (int jn = 0; jn < 4; ++jn) sa[jn] = (f32x4){0.f, 0.f, 0.f, 0.f};
#pragma unroll
        for (int kb2 = 0; kb2 < 4; ++kb2) {
#pragma unroll
          for (int jn = 0; jn < 4; ++jn) {
            bfrag bk = *(const bfrag*)(KsB + (jn * 16 + l15) * KS_STRIDE + (kb2 * 4 + quad) * 16);
            sa[jn] = __builtin_amdgcn_mfma_f32_16x16x32_bf16(aq[kb2], bk, sa[jn], 0, 0, 0);
          }
        }

        // online softmax, log2 domain (rows q = quad*4+r; cols over quad's 16 lanes)
        float z[4][4];   // [jn][r] raw (masked) scores; overwritten by p later
        float m2x[4];
#pragma unroll
        for (int r = 0; r < 4; ++r) {
#pragma unroll
          for (int jn = 0; jn < 4; ++jn) {
            float s = sa[jn][r];
            if (kt + jn * 16 + l15 > qpos[r]) s = NEGBIG;
            z[jn][r] = s;
          }
          float m0 = fmaxf(fmaxf(z[0][r], z[1][r]), fmaxf(z[2][r], z[3][r]));
          m0 = fmaxf(m0, __shfl_xor(m0, 1, 64));
          m0 = fmaxf(m0, __shfl_xor(m0, 2, 64));
          m0 = fmaxf(m0, __shfl_xor(m0, 4, 64));
          m0 = fmaxf(m0, __shfl_xor(m0, 8, 64));
          m2x[r] = m0 * C1;
        }

        bool ok = (m2x[0] <= m2_i[0] + DEFER2) && (m2x[1] <= m2_i[1] + DEFER2) &&
                  (m2x[2] <= m2_i[2] + DEFER2) && (m2x[3] <= m2_i[3] + DEFER2);
        if (__all(ok)) {
          // T13 defer path: keep old max, no O-rescale (P bounded by e^8)
#pragma unroll
          for (int r = 0; r < 4; ++r) {
            float rs = 0.f;
#pragma unroll
            for (int jn = 0; jn < 4; ++jn) {
              float pv = exp2f(z[jn][r] * C1 - m2_i[r]);
              z[jn][r] = pv;
              rs += pv;
            }
            rs += __shfl_xor(rs, 1, 64);
            rs += __shfl_xor(rs, 2, 64);
            rs += __shfl_xor(rs, 4, 64);
            rs += __shfl_xor(rs, 8, 64);
            l_i[r] += rs;
          }
        } else {
          float alpha[4];
#pragma unroll
          for (int r = 0; r < 4; ++r) {
            float m2n = fmaxf(m2_i[r], m2x[r]);
            float al = exp2f(m2_i[r] - m2n);
            float rs = 0.f;
#pragma unroll
            for (int jn = 0; jn < 4; ++jn) {
              float pv = exp2f(z[jn][r] * C1 - m2n);
              z[jn][r] = pv;
              rs += pv;
            }
            rs += __shfl_xor(rs, 1, 64);
            rs += __shfl_xor(rs, 2, 64);
            rs += __shfl_xor(rs, 4, 64);
            rs += __shfl_xor(rs, 8, 64);
            l_i[r] = l_i[r] * al + rs;
            m2_i[r] = m2n;
            alpha[r] = al;
          }
#pragma unroll
          for (int jd = 0; jd < 8; ++jd) {
            oa[jd][0] *= alpha[0];
            oa[jd][1] *= alpha[1];
            oa[jd][2] *= alpha[2];
            oa[jd][3] *= alpha[3];
          }
        }

        // P: C-layout -> A-layout via per-wave LDS region (padded)
#pragma unroll
        for (int r = 0; r < 4; ++r) {
          int q = quad * 4 + r;
#pragma unroll
          for (int jn = 0; jn < 4; ++jn)
            *(u16*)(myPsB + q * PS_STRIDE + (jn * 16 + l15) * 2) = f2bf(z[jn][r]);
        }
        bfrag ap0 = *(const bfrag*)(myPsB + l15 * PS_STRIDE + quad * 16);
        bfrag ap1 = *(const bfrag*)(myPsB + l15 * PS_STRIDE + 64 + quad * 16);
        // O += P V   (K-dim = 64 tokens = two mfma per 16-d block)
#pragma unroll
        for (int jd = 0; jd < 8; ++jd) {
          int d = jd * 16 + l15;
          bfrag bv0 = *(const bfrag*)(VtB + d * VT_STRIDE + quad * 16);
          bfrag bv1 = *(const bfrag*)(VtB + d * VT_STRIDE + 64 + quad * 16);
          oa[jd] = __builtin_amdgcn_mfma_f32_16x16x32_bf16(ap0, bv0, oa[jd], 0, 0, 0);
          oa[jd] = __builtin_amdgcn_mfma_f32_16x16x32_bf16(ap1, bv1, oa[jd], 0, 0, 0);
        }
      }
    }

    // normalize + write O[token][h*128+d] (input A of the output GEMM)
#pragma unroll
    for (int r = 0; r < 4; ++r) {
      float inv = 1.0f / fmaxf(l_i[r], 1e-30f);
      size_t trow = (size_t)b * SEQ + qw + quad * 4 + r;
#pragma unroll
      for (int jd = 0; jd < 8; ++jd)
        O[trow * 2048 + (size_t)h * HD + jd * 16 + l15] = f2bf(oa[jd][r] * inv);
    }
  }
}

// ---------------------------------------------------------------------------
extern "C" void kernel_launch(void* const* d_in, const int* in_sizes, int n_in,
                              void* d_out, int out_size, void* d_ws, size_t ws_size,
                              hipStream_t stream) {
  (void)in_sizes; (void)n_in; (void)out_size;
  const float* xf  = (const float*)d_in[0];
  const float* wqf = (const float*)d_in[1];
  const float* wkf = (const float*)d_in[2];
  const float* wvf = (const float*)d_in[3];
  const float* wof = (const float*)d_in[4];
  const int* positions = (const int*)d_in[7];
  const int* btab      = (const int*)d_in[10];
  float* out = (float*)d_out;

  // workspace carve-up (bf16 elements). woT FIRST so the obuf fallback
  // (aliasing wqkvT+xbf) can never clobber it.
  u16* ws    = (u16*)d_ws;
  u16* woT   = ws;                                  // [2048][2048]
  u16* wqkvT = woT + (size_t)2048 * 2048;           // [4096][2048]  (wq^T|wk^T|wv^T)
  u16* xbf   = wqkvT + (size_t)4096 * 2048;         // [8192][2048]
  u16* xqkv  = xbf + (size_t)8192 * 2048;           // [8192][4096]
  u16* qb    = xqkv + (size_t)8192 * 4096;          // [8][16][1024][128]
  u16* kbuf  = qb + (size_t)8192 * 2048;            // [512][8][16][128] paged
  u16* vbuf  = kbuf + (size_t)8192 * 1024;          // [512][8][16][128] paged
  u16* wsend = vbuf + (size_t)8192 * 1024;

  size_t base_elems = (size_t)(wsend - ws);
  size_t obuf_elems = (size_t)8192 * 2048;
  u16* obuf;
  if (ws_size >= (base_elems + obuf_elems) * sizeof(u16))
    obuf = wsend;                                    // dedicated region
  else
    obuf = wqkvT;                                    // alias dead wqkvT+xbf span

  if (ws_size < base_elems * sizeof(u16)) return;    // insufficient scratch

  // 1) convert x to bf16; transpose+convert weights into B^T layout
  f32_to_bf16<<<dim3(8192), 256, 0, stream>>>(xf, xbf, (size_t)8192 * 2048);
  ktranspose_f<<<dim3(32, 32), 256, 0, stream>>>(wqf, wqkvT, 2048, 2048);
  ktranspose_f<<<dim3(16, 32), 256, 0, stream>>>(wkf, wqkvT + (size_t)2048 * 2048, 2048, 1024);
  ktranspose_f<<<dim3(16, 32), 256, 0, stream>>>(wvf, wqkvT + (size_t)3072 * 2048, 2048, 1024);
  ktranspose_f<<<dim3(32, 32), 256, 0, stream>>>(wof, woT, 2048, 2048);
  // 2) fused QKV projection: [8192,2048] @ [2048,4096] -> bf16
  gemm_bt<u16><<<dim3(32, 64), 256, 0, stream>>>(xbf, wqkvT, xqkv, 8192, 4096, 2048);
  // 3) RoPE + scatter into Q buffer and paged K/V caches
  rope_scatter<<<dim3(8192), 256, 0, stream>>>(xqkv, positions, btab, qb, kbuf, vbuf);
  // 4) causal GQA flash attention over the paged cache
  //    512 blocks x 512 threads: each block = one (b,h) x paired q-tiles (y,7-y)
  //    -> exactly 18 KVT=64 iterations per block (uniform), 2 blocks/CU.
  attn_kernel<<<dim3(512), 512, 0, stream>>>(qb, kbuf, vbuf, positions, btab, obuf);
  // 5) output projection: [8192,2048] @ [2048,2048] -> fp32 out
  gemm_bt<float><<<dim3(16, 64), 256, 0, stream>>>(obuf, woT, out, 8192, 2048, 2048);
}

// Round 4
// 621.182 us; speedup vs baseline: 1.2035x; 1.2035x over previous
//
#include <hip/hip_runtime.h>
#include <stdint.h>

// Problem constants (Attention_39556648796173)
// Inputs: float32 buffers (per reference dtypes). Output: float32.
// Compute core: bf16 MFMA (comparison tolerance is bf16-scaled: 2% of max).
#define TTOK  8192
#define DIMM  2048
#define NH    16
#define NKV   8
#define HD    128
#define SEQ   1024
#define BATCH 8
#define BLKSZ 16

typedef unsigned short u16;
typedef __attribute__((ext_vector_type(8))) short bfrag;   // 8 x bf16 (4 VGPRs)
typedef __attribute__((ext_vector_type(4))) float f32x4;   // MFMA accumulator

__device__ __forceinline__ float bf2f(u16 u) {
  unsigned int v = ((unsigned int)u) << 16;
  float f; __builtin_memcpy(&f, &v, 4); return f;
}
__device__ __forceinline__ u16 f2bf(float f) {
  unsigned int v; __builtin_memcpy(&v, &f, 4);
  v = v + 0x7FFFu + ((v >> 16) & 1u);   // RNE
  return (u16)(v >> 16);
}

// async global->LDS, 16B per lane; LDS dest = wave-uniform base + lane*16
__device__ __forceinline__ void gll16(const void* g, void* l) {
  __builtin_amdgcn_global_load_lds(
      (__attribute__((address_space(1))) void*)(g),
      (__attribute__((address_space(3))) void*)(l), 16, 0, 0);
}
// full drain (vmcnt=0, expcnt=0, lgkmcnt=0) + compiler memory fence
__device__ __forceinline__ void hard_fence() {
  asm volatile("" ::: "memory");
  __builtin_amdgcn_s_waitcnt(0);
  asm volatile("" ::: "memory");
}

// ---------------------------------------------------------------------------
// fp32 -> bf16 bulk convert (n multiple of 2048); 8 elems/thread
// ---------------------------------------------------------------------------
__global__ __launch_bounds__(256) void f32_to_bf16(const float* __restrict__ in,
                                                   u16* __restrict__ out, size_t n) {
  size_t i = ((size_t)blockIdx.x * 256 + threadIdx.x) * 8;
  if (i >= n) return;
  float4 a = *(const float4*)(in + i);
  float4 b = *(const float4*)(in + i + 4);
  union { u16 o[8]; uint4 v; } u;
  u.o[0] = f2bf(a.x); u.o[1] = f2bf(a.y); u.o[2] = f2bf(a.z); u.o[3] = f2bf(a.w);
  u.o[4] = f2bf(b.x); u.o[5] = f2bf(b.y); u.o[6] = f2bf(b.z); u.o[7] = f2bf(b.w);
  *(uint4*)(out + i) = u.v;
}

// ---------------------------------------------------------------------------
// Tiled transpose + fp32->bf16: out[n][k] = bf16(in[k][n]), K,N multiples of 64
// ---------------------------------------------------------------------------
__global__ __launch_bounds__(256) void ktranspose_f(const float* __restrict__ in,
                                                    u16* __restrict__ out, int K, int N) {
  __shared__ __align__(16) u16 tile[64 * 65];
  int n0 = blockIdx.x * 64, k0 = blockIdx.y * 64;
  int tx = threadIdx.x & 63, ty = threadIdx.x >> 6;
  for (int r = 0; r < 16; ++r) {
    int kk = r * 4 + ty;
    tile[kk * 65 + tx] = f2bf(in[(size_t)(k0 + kk) * N + n0 + tx]);
  }
  __syncthreads();
  for (int r = 0; r < 16; ++r) {
    int nn = r * 4 + ty;
    out[(size_t)(n0 + nn) * K + k0 + tx] = tile[tx * 65 + nn];
  }
}

// ---------------------------------------------------------------------------
// m97-style GEMM: C[M,N] = A[M,K] @ B, with B given transposed (Bt[N,K]).
// 128x128 tile, BK=32, 4 waves (2x2 of 64x64), mfma 16x16x32 bf16.
// ---------------------------------------------------------------------------
template <typename OutT>
__global__ __launch_bounds__(256) void gemm_bt(const u16* __restrict__ A,
                                               const u16* __restrict__ Bt,
                                               OutT* __restrict__ C,
                                               int M, int N, int K) {
  __shared__ __align__(16) u16 As[128 * 32];
  __shared__ __align__(16) u16 Bs[128 * 32];
  int tid = threadIdx.x;
  int wave = tid >> 6, lane = tid & 63, quad = lane >> 4, l15 = lane & 15;
  int m0 = blockIdx.y * 128, n0 = blockIdx.x * 128;
  int wm = (wave >> 1) * 64, wn = (wave & 1) * 64;

  f32x4 acc[4][4];
  for (int i = 0; i < 4; ++i)
    for (int j = 0; j < 4; ++j) acc[i][j] = (f32x4){0.f, 0.f, 0.f, 0.f};

  int g0 = wave * 64 + lane;            // granules 0..255
  int g1 = 256 + wave * 64 + lane;      // granules 256..511
  const u16* Arow0 = A + (size_t)(m0 + (g0 >> 2)) * K + (g0 & 3) * 8;
  const u16* Arow1 = A + (size_t)(m0 + (g1 >> 2)) * K + (g1 & 3) * 8;
  const u16* Brow0 = Bt + (size_t)(n0 + (g0 >> 2)) * K + (g0 & 3) * 8;
  const u16* Brow1 = Bt + (size_t)(n0 + (g1 >> 2)) * K + (g1 & 3) * 8;
  char* AsB = (char*)As;
  char* BsB = (char*)Bs;
  int lds0 = wave * 1024, lds1 = 4096 + wave * 1024;  // wave-uniform bases

  for (int k0 = 0; k0 < K; k0 += 32) {
    __syncthreads();                 // all waves done reading previous tile
    asm volatile("" ::: "memory");
    gll16(Arow0 + k0, AsB + lds0);
    gll16(Arow1 + k0, AsB + lds1);
    gll16(Brow0 + k0, BsB + lds0);
    gll16(Brow1 + k0, BsB + lds1);
    hard_fence();                    // own DMA fully landed in LDS
    __syncthreads();                 // everyone's DMA landed

    bfrag af[4], bfv[4];
    for (int im = 0; im < 4; ++im) {
      int m = wm + im * 16 + l15;
      af[im] = *(const bfrag*)(AsB + m * 64 + quad * 16);
    }
    for (int jn = 0; jn < 4; ++jn) {
      int n = wn + jn * 16 + l15;
      bfv[jn] = *(const bfrag*)(BsB + n * 64 + quad * 16);
    }
    for (int im = 0; im < 4; ++im)
      for (int jn = 0; jn < 4; ++jn)
        acc[im][jn] = __builtin_amdgcn_mfma_f32_16x16x32_bf16(af[im], bfv[jn], acc[im][jn], 0, 0, 0);
  }

  // C/D layout: col = lane&15, row = quad*4 + reg  (m89/m91 verified)
  for (int im = 0; im < 4; ++im)
    for (int jn = 0; jn < 4; ++jn)
      for (int r = 0; r < 4; ++r) {
        int row = m0 + wm + im * 16 + quad * 4 + r;
        int col = n0 + wn + jn * 16 + l15;
        if constexpr (__is_same(OutT, float))
          C[(size_t)row * N + col] = acc[im][jn][r];
        else
          C[(size_t)row * N + col] = f2bf(acc[im][jn][r]);
      }
}

// ---------------------------------------------------------------------------
// RoPE (interleaved pairs) + scatter into Q[b][h][s][d] (token order) and
// paged K/V caches [blk][kvh][off][d] honoring block_tables.
// ---------------------------------------------------------------------------
__global__ __launch_bounds__(256) void rope_scatter(const u16* __restrict__ xqkv,
                                                    const int* __restrict__ positions,
                                                    const int* __restrict__ btab,
                                                    u16* __restrict__ qb,
                                                    u16* __restrict__ kb,
                                                    u16* __restrict__ vbuf) {
  int t = blockIdx.x;
  int tid = threadIdx.x;
  int b = t >> 10, srow = t & 1023;
  int pos = positions[t];
  int blk = btab[b * (SEQ / BLKSZ) + (pos >> 4)];
  int off = pos & (BLKSZ - 1);
  int c0 = tid * 16;

  struct __align__(16) { uint4 a, bq; } vv, oo;
  const u16* src = xqkv + (size_t)t * 4096 + c0;
  vv.a  = *(const uint4*)src;
  vv.bq = *(const uint4*)(src + 8);
  const u16* v = (const u16*)&vv;
  u16* o = (u16*)&oo;

  if (c0 < 3072) {  // Q or K section: apply RoPE on (even,odd) pairs
    int dbase = c0 & 127;
    float fpos = (float)pos;
    for (int j = 0; j < 8; ++j) {
      int i = (dbase >> 1) + j;                       // freq index 0..63
      float inv = exp2f(-(float)i * (13.287712379549449f / 64.0f)); // 10000^(-i/64)
      float ang = fpos * inv;
      float sn, cs;
      sincosf(ang, &sn, &cs);
      float fr = bf2f(v[2 * j]), fi = bf2f(v[2 * j + 1]);
      o[2 * j]     = f2bf(fr * cs - fi * sn);
      o[2 * j + 1] = f2bf(fr * sn + fi * cs);
    }
  } else {
    for (int j = 0; j < 16; ++j) o[j] = v[j];
  }

  u16* dst;
  if (c0 < 2048) {
    int head = c0 >> 7, d0 = c0 & 127;
    dst = qb + (((size_t)(b * NH + head)) * SEQ + srow) * HD + d0;
  } else if (c0 < 3072) {
    int cc = c0 - 2048;
    int kvh = cc >> 7, d0 = cc & 127;
    dst = kb + (((size_t)(blk * NKV + kvh) * BLKSZ + off)) * HD + d0;
  } else {
    int cc = c0 - 3072;
    int kvh = cc >> 7, d0 = cc & 127;
    dst = vbuf + (((size_t)(blk * NKV + kvh) * BLKSZ + off)) * HD + d0;
  }
  *(uint4*)dst = oo.a;
  *(uint4*)(dst + 8) = oo.bq;
}

// ---------------------------------------------------------------------------
// Flash attention v2, paged cache — KVT=64 + T14, SPILL-FIXED version.
//
// Round-3 post-mortem: __launch_bounds__(512,4) made the compiler allocate
// only 64 VGPRs; the working set (oa 32 + aq 16 + prefetch 16 + scores 16+)
// spilled to scratch -> WRITE_SIZE 32MB->530MB, FETCH +235MB of spill reads,
// 4 TB/s of garbage traffic, attn 199->261us. The KVT=64/T14 structure was
// never actually evaluated.
//
// Fixes vs round 3:
//  * __launch_bounds__(512) only (round-1's working config: 84 VGPRs clean).
//  * score array z[4][4] folded into sa[4] in place (-16 VGPRs): mask, max,
//    and exp all overwrite the MFMA accumulator registers directly.
// Everything else unchanged: 9216 uniform block-iterations (KVT=64, q-tile
// pairing), T14 register prefetch (next tile's loads issued after barrier
// #2, drained by next iteration's barrier #1 under ~1000 cycles of MFMA +
// softmax), log2-domain softmax, T13 defer-max, padded LDS strides.
// ---------------------------------------------------------------------------
#define KVT 64
#define KS_STRIDE 272   // bytes per K token row (128*2 + 16 pad)
#define VT_STRIDE 144   // bytes per V d row (64*2 + 16 pad)
#define PS_STRIDE 144   // bytes per P q row (64*2 + 16 pad)

__global__ __launch_bounds__(512) void attn_kernel(const u16* __restrict__ Q,
                                                   const u16* __restrict__ Kc,
                                                   const u16* __restrict__ Vc,
                                                   const int* __restrict__ positions,
                                                   const int* __restrict__ btab,
                                                   u16* __restrict__ O) {
  __shared__ __align__(16) u16 Ks[KVT * (KS_STRIDE / 2)];     // [tok][d] padded, 17408 B
  __shared__ __align__(16) u16 Vt[HD * (VT_STRIDE / 2)];      // [d][tok] padded, 18432 B
  __shared__ __align__(16) u16 Ps[8 * 16 * (PS_STRIDE / 2)];  // [wave][q][tok], 18432 B
  const float SM_SCALE = 0.08838834764831845f; // 1/sqrt(128)
  const float LOG2E    = 1.4426950408889634f;
  const float C1       = SM_SCALE * LOG2E;     // score -> log2-domain
  const float NEGBIG   = -30000.0f;
  const float NEGINIT  = -1e30f;
  const float DEFER2   = 8.0f * LOG2E;         // T13 threshold in log2 domain

  int tid = threadIdx.x;
  int wave = tid >> 6, lane = tid & 63, quad = lane >> 4, l15 = lane & 15;
  int bid = blockIdx.x;
  int bh = bid >> 2, pr = bid & 3;             // pair index 0..3
  int b = bh >> 4, h = bh & 15, kvh = h >> 1;
  const int* btrow = btab + b * (SEQ / BLKSZ);

  char* KsB = (char*)Ks;
  char* VtB = (char*)Vt;
  char* myPsB = (char*)Ps + wave * 16 * PS_STRIDE;

  // K staging decode: 1024 granules of 16B (64 tok x 16 dg), 2 per thread
  int tokA = tid >> 4;          // rows 0..31
  int tokB = tokA + 32;         // rows 32..63
  int dgK  = tid & 15;
  // V staging decode: 2 tokens x 8 d per thread (transpose in regs)
  int tokV = (tid & 31) * 2;    // even token 0..62 (odd = +1, same cache blk)
  int vd0  = (tid >> 5) * 8;    // 0..120

  uint4 kr0, kr1, vr0, vr1;     // T14 prefetch registers

  // load tile starting at token index kti (multiple of 64) into regs
  auto load_tile = [&](int kti) {
    int i0 = kti >> 4;
    int b0 = btrow[i0], b1 = btrow[i0 + 1], b2 = btrow[i0 + 2], b3 = btrow[i0 + 3];
    const u16* KA = Kc + ((size_t)(((tokA < 16) ? b0 : b1) * NKV + kvh) * BLKSZ + (tokA & 15)) * HD + dgK * 8;
    const u16* KB = Kc + ((size_t)(((tokB < 48) ? b2 : b3) * NKV + kvh) * BLKSZ + (tokB & 15)) * HD + dgK * 8;
    kr0 = *(const uint4*)KA;
    kr1 = *(const uint4*)KB;
    int bv = (tokV < 16) ? b0 : (tokV < 32) ? b1 : (tokV < 48) ? b2 : b3;
    const u16* VA = Vc + ((size_t)(bv * NKV + kvh) * BLKSZ + (tokV & 15)) * HD + vd0;
    vr0 = *(const uint4*)VA;
    vr1 = *(const uint4*)(VA + HD);
  };

  for (int pass = 0; pass < 2; ++pass) {
    int yt = pass ? (7 - pr) : pr;             // q-tile of this pass
    int q0 = yt * 128;
    int qw = q0 + wave * 16;                   // this wave's 16 rows

    const u16* Qbase = Q + ((size_t)bh * SEQ + qw) * HD;

    // Q fragments (A-layout: m=lane&15, k=quad*8+j): 4 k-blocks
    bfrag aq[4];
#pragma unroll
    for (int kb2 = 0; kb2 < 4; ++kb2)
      aq[kb2] = *(const bfrag*)(Qbase + (size_t)l15 * HD + kb2 * 32 + quad * 8);

    int qpos[4];
#pragma unroll
    for (int r = 0; r < 4; ++r)
      qpos[r] = positions[(size_t)b * SEQ + qw + quad * 4 + r];

    f32x4 oa[8];
#pragma unroll
    for (int jd = 0; jd < 8; ++jd) oa[jd] = (f32x4){0.f, 0.f, 0.f, 0.f};
    float m2_i[4], l_i[4];
#pragma unroll
    for (int r = 0; r < 4; ++r) { m2_i[r] = NEGINIT; l_i[r] = 0.f; }

    int kend = q0 + 128;
    load_tile(0);                              // pass prologue prefetch

    for (int kt = 0; kt < kend; kt += KVT) {
      __syncthreads();     // #1: prev tile's LDS reads done; drains vmcnt ->
                           //     prefetched regs landed (hidden under compute)
      // regs -> LDS
      *(uint4*)(KsB + tokA * KS_STRIDE + dgK * 16) = kr0;
      *(uint4*)(KsB + tokB * KS_STRIDE + dgK * 16) = kr1;
      {
        const u16* p0 = (const u16*)&vr0;
        const u16* p1 = (const u16*)&vr1;
#pragma unroll
        for (int jj = 0; jj < 8; ++jj) {
          unsigned int val = (unsigned int)p0[jj] | ((unsigned int)p1[jj] << 16);
          *(unsigned int*)(VtB + (vd0 + jj) * VT_STRIDE + tokV * 2) = val;
        }
      }
      __syncthreads();     // #2: LDS tile ready (nothing else pending)

      // T14: issue next tile's loads now; they fly during compute and are
      // drained by the next iteration's barrier #1.
      if (kt + KVT < kend) load_tile(kt + KVT);

      if (kt <= qw + 15) {                     // wave-uniform skip
        // S = Q K^T  (16 q x 64 tok)
        f32x4 sa[4];
#pragma unroll
        for (int jn = 0; jn < 4; ++jn) sa[jn] = (f32x4){0.f, 0.f, 0.f, 0.f};
#pragma unroll
        for (int kb2 = 0; kb2 < 4; ++kb2) {
#pragma unroll
          for (int jn = 0; jn < 4; ++jn) {
            bfrag bk = *(const bfrag*)(KsB + (jn * 16 + l15) * KS_STRIDE + (kb2 * 4 + quad) * 16);
            sa[jn] = __builtin_amdgcn_mfma_f32_16x16x32_bf16(aq[kb2], bk, sa[jn], 0, 0, 0);
          }
        }

        // online softmax, log2 domain; scores masked/expd IN PLACE in sa
        float m2x[4];
#pragma unroll
        for (int r = 0; r < 4; ++r) {
#pragma unroll
          for (int jn = 0; jn < 4; ++jn) {
            float s = sa[jn][r];
            if (kt + jn * 16 + l15 > qpos[r]) s = NEGBIG;
            sa[jn][r] = s;
          }
          float m0 = fmaxf(fmaxf(sa[0][r], sa[1][r]), fmaxf(sa[2][r], sa[3][r]));
          m0 = fmaxf(m0, __shfl_xor(m0, 1, 64));
          m0 = fmaxf(m0, __shfl_xor(m0, 2, 64));
          m0 = fmaxf(m0, __shfl_xor(m0, 4, 64));
          m0 = fmaxf(m0, __shfl_xor(m0, 8, 64));
          m2x[r] = m0 * C1;
        }

        bool ok = (m2x[0] <= m2_i[0] + DEFER2) && (m2x[1] <= m2_i[1] + DEFER2) &&
                  (m2x[2] <= m2_i[2] + DEFER2) && (m2x[3] <= m2_i[3] + DEFER2);
        if (__all(ok)) {
          // T13 defer path: keep old max, no O-rescale (P bounded by e^8)
#pragma unroll
          for (int r = 0; r < 4; ++r) {
            float rs = 0.f;
#pragma unroll
            for (int jn = 0; jn < 4; ++jn) {
              float pv = exp2f(sa[jn][r] * C1 - m2_i[r]);
              sa[jn][r] = pv;
              rs += pv;
            }
            rs += __shfl_xor(rs, 1, 64);
            rs += __shfl_xor(rs, 2, 64);
            rs += __shfl_xor(rs, 4, 64);
            rs += __shfl_xor(rs, 8, 64);
            l_i[r] += rs;
          }
        } else {
          float alpha[4];
#pragma unroll
          for (int r = 0; r < 4; ++r) {
            float m2n = fmaxf(m2_i[r], m2x[r]);
            float al = exp2f(m2_i[r] - m2n);
            float rs = 0.f;
#pragma unroll
            for (int jn = 0; jn < 4; ++jn) {
              float pv = exp2f(sa[jn][r] * C1 - m2n);
              sa[jn][r] = pv;
              rs += pv;
            }
            rs += __shfl_xor(rs, 1, 64);
            rs += __shfl_xor(rs, 2, 64);
            rs += __shfl_xor(rs, 4, 64);
            rs += __shfl_xor(rs, 8, 64);
            l_i[r] = l_i[r] * al + rs;
            m2_i[r] = m2n;
            alpha[r] = al;
          }
#pragma unroll
          for (int jd = 0; jd < 8; ++jd) {
            oa[jd][0] *= alpha[0];
            oa[jd][1] *= alpha[1];
            oa[jd][2] *= alpha[2];
            oa[jd][3] *= alpha[3];
          }
        }

        // P: C-layout -> A-layout via per-wave LDS region (padded)
#pragma unroll
        for (int r = 0; r < 4; ++r) {
          int q = quad * 4 + r;
#pragma unroll
          for (int jn = 0; jn < 4; ++jn)
            *(u16*)(myPsB + q * PS_STRIDE + (jn * 16 + l15) * 2) = f2bf(sa[jn][r]);
        }
        bfrag ap0 = *(const bfrag*)(myPsB + l15 * PS_STRIDE + quad * 16);
        bfrag ap1 = *(const bfrag*)(myPsB + l15 * PS_STRIDE + 64 + quad * 16);
        // O += P V   (K-dim = 64 tokens = two mfma per 16-d block)
#pragma unroll
        for (int jd = 0; jd < 8; ++jd) {
          int d = jd * 16 + l15;
          bfrag bv0 = *(const bfrag*)(VtB + d * VT_STRIDE + quad * 16);
          bfrag bv1 = *(const bfrag*)(VtB + d * VT_STRIDE + 64 + quad * 16);
          oa[jd] = __builtin_amdgcn_mfma_f32_16x16x32_bf16(ap0, bv0, oa[jd], 0, 0, 0);
          oa[jd] = __builtin_amdgcn_mfma_f32_16x16x32_bf16(ap1, bv1, oa[jd], 0, 0, 0);
        }
      }
    }

    // normalize + write O[token][h*128+d] (input A of the output GEMM)
#pragma unroll
    for (int r = 0; r < 4; ++r) {
      float inv = 1.0f / fmaxf(l_i[r], 1e-30f);
      size_t trow = (size_t)b * SEQ + qw + quad * 4 + r;
#pragma unroll
      for (int jd = 0; jd < 8; ++jd)
        O[trow * 2048 + (size_t)h * HD + jd * 16 + l15] = f2bf(oa[jd][r] * inv);
    }
  }
}

// ---------------------------------------------------------------------------
extern "C" void kernel_launch(void* const* d_in, const int* in_sizes, int n_in,
                              void* d_out, int out_size, void* d_ws, size_t ws_size,
                              hipStream_t stream) {
  (void)in_sizes; (void)n_in; (void)out_size;
  const float* xf  = (const float*)d_in[0];
  const float* wqf = (const float*)d_in[1];
  const float* wkf = (const float*)d_in[2];
  const float* wvf = (const float*)d_in[3];
  const float* wof = (const float*)d_in[4];
  const int* positions = (const int*)d_in[7];
  const int* btab      = (const int*)d_in[10];
  float* out = (float*)d_out;

  // workspace carve-up (bf16 elements). woT FIRST so the obuf fallback
  // (aliasing wqkvT+xbf) can never clobber it.
  u16* ws    = (u16*)d_ws;
  u16* woT   = ws;                                  // [2048][2048]
  u16* wqkvT = woT + (size_t)2048 * 2048;           // [4096][2048]  (wq^T|wk^T|wv^T)
  u16* xbf   = wqkvT + (size_t)4096 * 2048;         // [8192][2048]
  u16* xqkv  = xbf + (size_t)8192 * 2048;           // [8192][4096]
  u16* qb    = xqkv + (size_t)8192 * 4096;          // [8][16][1024][128]
  u16* kbuf  = qb + (size_t)8192 * 2048;            // [512][8][16][128] paged
  u16* vbuf  = kbuf + (size_t)8192 * 1024;          // [512][8][16][128] paged
  u16* wsend = vbuf + (size_t)8192 * 1024;

  size_t base_elems = (size_t)(wsend - ws);
  size_t obuf_elems = (size_t)8192 * 2048;
  u16* obuf;
  if (ws_size >= (base_elems + obuf_elems) * sizeof(u16))
    obuf = wsend;                                    // dedicated region
  else
    obuf = wqkvT;                                    // alias dead wqkvT+xbf span

  if (ws_size < base_elems * sizeof(u16)) return;    // insufficient scratch

  // 1) convert x to bf16; transpose+convert weights into B^T layout
  f32_to_bf16<<<dim3(8192), 256, 0, stream>>>(xf, xbf, (size_t)8192 * 2048);
  ktranspose_f<<<dim3(32, 32), 256, 0, stream>>>(wqf, wqkvT, 2048, 2048);
  ktranspose_f<<<dim3(16, 32), 256, 0, stream>>>(wkf, wqkvT + (size_t)2048 * 2048, 2048, 1024);
  ktranspose_f<<<dim3(16, 32), 256, 0, stream>>>(wvf, wqkvT + (size_t)3072 * 2048, 2048, 1024);
  ktranspose_f<<<dim3(32, 32), 256, 0, stream>>>(wof, woT, 2048, 2048);
  // 2) fused QKV projection: [8192,2048] @ [2048,4096] -> bf16
  gemm_bt<u16><<<dim3(32, 64), 256, 0, stream>>>(xbf, wqkvT, xqkv, 8192, 4096, 2048);
  // 3) RoPE + scatter into Q buffer and paged K/V caches
  rope_scatter<<<dim3(8192), 256, 0, stream>>>(xqkv, positions, btab, qb, kbuf, vbuf);
  // 4) causal GQA flash attention over the paged cache
  //    512 blocks x 512 threads: each block = one (b,h) x paired q-tiles (y,7-y)
  //    -> exactly 18 KVT=64 iterations per block (uniform), 2 blocks/CU.
  attn_kernel<<<dim3(512), 512, 0, stream>>>(qb, kbuf, vbuf, positions, btab, obuf);
  // 5) output projection: [8192,2048] @ [2048,2048] -> fp32 out
  gemm_bt<float><<<dim3(16, 64), 256, 0, stream>>>(obuf, woT, out, 8192, 2048, 2048);
}

// Round 6
// 560.912 us; speedup vs baseline: 1.3329x; 1.1074x over previous
//
#include <hip/hip_runtime.h>
#include <stdint.h>

// Problem constants (Attention_39556648796173)
#define TTOK  8192
#define DIMM  2048
#define NH    16
#define NKV   8
#define HD    128
#define SEQ   1024
#define BATCH 8
#define BLKSZ 16

typedef unsigned short u16;
typedef __attribute__((ext_vector_type(8))) short bfrag;   // 8 x bf16 (4 VGPRs)
typedef __attribute__((ext_vector_type(4))) float f32x4;   // MFMA accumulator

__device__ __forceinline__ float bf2f(u16 u) {
  unsigned int v = ((unsigned int)u) << 16;
  float f; __builtin_memcpy(&f, &v, 4); return f;
}
__device__ __forceinline__ u16 f2bf(float f) {
  unsigned int v; __builtin_memcpy(&v, &f, 4);
  v = v + 0x7FFFu + ((v >> 16) & 1u);   // RNE
  return (u16)(v >> 16);
}

// async global->LDS, 16B per lane; LDS dest = wave-uniform base + lane*16
__device__ __forceinline__ void gll16(const void* g, void* l) {
  __builtin_amdgcn_global_load_lds(
      (__attribute__((address_space(1))) void*)(g),
      (__attribute__((address_space(3))) void*)(l), 16, 0, 0);
}

// Rule-18-hardened barrier: drain own DS ops, pin scheduling, then barrier.
// Guarantees: no wave crosses with outstanding ds_reads, so post-barrier
// gll16 DMA staging can never overwrite a region still being read.
__device__ __forceinline__ void lds_barrier() {
  asm volatile("s_waitcnt lgkmcnt(0)" ::: "memory");
  __builtin_amdgcn_sched_barrier(0);
  __builtin_amdgcn_s_barrier();
}

// ---------------------------------------------------------------------------
// fp32 -> bf16 bulk convert (n multiple of 2048); 8 elems/thread
// ---------------------------------------------------------------------------
__global__ __launch_bounds__(256) void f32_to_bf16(const float* __restrict__ in,
                                                   u16* __restrict__ out, size_t n) {
  size_t i = ((size_t)blockIdx.x * 256 + threadIdx.x) * 8;
  if (i >= n) return;
  float4 a = *(const float4*)(in + i);
  float4 b = *(const float4*)(in + i + 4);
  union { u16 o[8]; uint4 v; } u;
  u.o[0] = f2bf(a.x); u.o[1] = f2bf(a.y); u.o[2] = f2bf(a.z); u.o[3] = f2bf(a.w);
  u.o[4] = f2bf(b.x); u.o[5] = f2bf(b.y); u.o[6] = f2bf(b.z); u.o[7] = f2bf(b.w);
  *(uint4*)(out + i) = u.v;
}

// ---------------------------------------------------------------------------
// Tiled transpose + fp32->bf16: out[n][k] = bf16(in[k][n]), K,N multiples of 64
// ---------------------------------------------------------------------------
__global__ __launch_bounds__(256) void ktranspose_f(const float* __restrict__ in,
                                                    u16* __restrict__ out, int K, int N) {
  __shared__ __align__(16) u16 tile[64 * 65];
  int n0 = blockIdx.x * 64, k0 = blockIdx.y * 64;
  int tx = threadIdx.x & 63, ty = threadIdx.x >> 6;
  for (int r = 0; r < 16; ++r) {
    int kk = r * 4 + ty;
    tile[kk * 65 + tx] = f2bf(in[(size_t)(k0 + kk) * N + n0 + tx]);
  }
  __syncthreads();
  for (int r = 0; r < 16; ++r) {
    int nn = r * 4 + ty;
    out[(size_t)(n0 + nn) * K + k0 + tx] = tile[tx * 65 + nn];
  }
}

// ---------------------------------------------------------------------------
// 256x256 phase-interleaved GEMM (m201-style): C[M,N] = A[M,K] @ Bt[N,K]^T.
// BK=64, 8 waves (2Mx4N), per-wave 128x64 output, mfma 16x16x32 bf16.
// 128 KiB LDS double-buffer, 1 block/CU.
//
// Schedule (per K-tile, 4 phases, ONE lds_barrier each, NO vmcnt(0) drains):
//   ph0: read A-half0 frags (8xb128) + B-half0 frags (4) -> 16 MFMA (mh0,nh0)
//   ph1: stage tile t+2 A-half0 + B-half0 (4 gll16)  [regions read at ph0]
//        read B-half1 (4) -> 16 MFMA (mh0,nh1) [A cached]
//   ph2: stage B-half1 (2)                           [read at ph1]
//        read A-half1 (8) -> 16 MFMA (mh1,nh1) [B1 cached]
//   ph3: stage A-half1 (2)                           [read at ph2]
//        16 MFMA (mh1,nh0) [A1 + B0 cached, register-only]
//        vmcnt(8)  <- counted (T4): tile t+1's 8 loads landed; t+2's stay
// Race-freedom: a region is staged only in the phase AFTER its reads, and
// lds_barrier drains lgkmcnt before any wave crosses (rule-18 hardened —
// compiler cannot defeat it by sinking MFMAs/waits past the barrier).
// Values needed across phases are register-cached, never re-read.
//
// Read swizzle (T2) with pre-swizzled gll16 source (rule 21, involution):
//   LDS slot (row,o) holds global byte o ^ ((row&7)<<4); frag reads XOR the
//   same term -> quad's 16 lanes spread over 8 distinct 16B slots, and a
//   full ds_read_b128 wave access covers each bank-group exactly 8x
//   (bandwidth-minimal, conflict-free).
// ---------------------------------------------------------------------------
template <typename OutT>
__global__ __launch_bounds__(512, 2) void gemm_bt8(const u16* __restrict__ A,
                                                   const u16* __restrict__ Bt,
                                                   OutT* __restrict__ C,
                                                   int M, int N, int K) {
  __shared__ __align__(16) u16 AS[2][256 * 64];   // [buf][256 rows x 64 k] 32KB each
  __shared__ __align__(16) u16 BS[2][256 * 64];
  (void)M;
  int tid = threadIdx.x;
  int w = tid >> 6, lane = tid & 63, quad = lane >> 4, l15 = lane & 15;
  int wr = w >> 2, wc = w & 3;          // 2 M-warps x 4 N-warps

  // XCD-bijective block swizzle (grid counts are multiples of 8 here)
  int nwg = gridDim.x * gridDim.y;
  int id = blockIdx.y * gridDim.x + blockIdx.x;
  int swz = (id & 7) * (nwg >> 3) + (id >> 3);
  int bx = swz % gridDim.x, by = swz / gridDim.x;
  int m0 = by * 256, n0 = bx * 256;

  size_t Kb = (size_t)K * 2;            // bytes per row
  int nt = K >> 6;                      // K-tiles of 64

  // staging: wave w covers 16-row chunks at half*128 + w*16 (+0, +8)
  int s_lr = lane >> 3;                           // row within 8-row chunk
  int s_lo = ((lane & 7) ^ s_lr) * 16;            // pre-swizzled byte in row
  auto stageA = [&](int half, int tk, char* As) {
    int rloc = half * 128 + w * 16;
    const char* src = (const char*)A + (size_t)(m0 + rloc + s_lr) * Kb + (size_t)tk * 128 + s_lo;
    char* dst = As + rloc * 128 + lane * 16;
    gll16(src, dst);
    gll16(src + 8 * Kb, dst + 1024);
  };
  auto stageB = [&](int half, int tk, char* Bs) {
    int rloc = half * 128 + w * 16;
    const char* src = (const char*)Bt + (size_t)(n0 + rloc + s_lr) * Kb + (size_t)tk * 128 + s_lo;
    char* dst = Bs + rloc * 128 + lane * 16;
    gll16(src, dst);
    gll16(src + 8 * Kb, dst + 1024);
  };

  f32x4 acc[2][4][2][2];                // [mh][f][nh][g]
#pragma unroll
  for (int mh = 0; mh < 2; ++mh)
#pragma unroll
    for (int f = 0; f < 4; ++f)
#pragma unroll
      for (int nh = 0; nh < 2; ++nh)
#pragma unroll
        for (int g = 0; g < 2; ++g) acc[mh][f][nh][g] = (f32x4){0.f, 0.f, 0.f, 0.f};

  // prologue: stage tiles 0 and 1 fully; wait tile 0 (8 newest stay in flight)
  stageA(0, 0, (char*)AS[0]); stageA(1, 0, (char*)AS[0]);
  stageB(0, 0, (char*)BS[0]); stageB(1, 0, (char*)BS[0]);
  if (nt > 1) {
    stageA(0, 1, (char*)AS[1]); stageA(1, 1, (char*)AS[1]);
    stageB(0, 1, (char*)BS[1]); stageB(1, 1, (char*)BS[1]);
    asm volatile("s_waitcnt vmcnt(8)" ::: "memory");
  } else {
    asm volatile("s_waitcnt vmcnt(0)" ::: "memory");
  }
  lds_barrier();

  int rswz = (l15 & 7) << 4;            // read-side swizzle term
  int aRow = wr * 64 + l15;             // + mh*128 + f*16
  int bRow = wc * 32 + l15;             // + nh*128 + g*16

  for (int t = 0; t < nt; ++t) {
    char* As = (char*)AS[t & 1];
    char* Bs = (char*)BS[t & 1];
    bool pre = (t + 2 < nt);
    bfrag aA[4][2], aB0[2][2], aB1[2][2];

    // ---- phase 0: (mh0, nh0) ----
#pragma unroll
    for (int f = 0; f < 4; ++f)
#pragma unroll
      for (int kk = 0; kk < 2; ++kk)
        aA[f][kk] = *(const bfrag*)(As + (aRow + f * 16) * 128 + ((kk * 64 + quad * 16) ^ rswz));
#pragma unroll
    for (int g = 0; g < 2; ++g)
#pragma unroll
      for (int kk = 0; kk < 2; ++kk)
        aB0[g][kk] = *(const bfrag*)(Bs + (bRow + g * 16) * 128 + ((kk * 64 + quad * 16) ^ rswz));
    __builtin_amdgcn_s_setprio(1);
#pragma unroll
    for (int f = 0; f < 4; ++f)
#pragma unroll
      for (int g = 0; g < 2; ++g)
#pragma unroll
        for (int kk = 0; kk < 2; ++kk)
          acc[0][f][0][g] = __builtin_amdgcn_mfma_f32_16x16x32_bf16(aA[f][kk], aB0[g][kk], acc[0][f][0][g], 0, 0, 0);
    __builtin_amdgcn_s_setprio(0);
    lds_barrier();

    // ---- phase 1: stage(t+2: A-h0, B-h0); (mh0, nh1) ----
    if (pre) { stageA(0, t + 2, As); stageB(0, t + 2, Bs); }
#pragma unroll
    for (int g = 0; g < 2; ++g)
#pragma unroll
      for (int kk = 0; kk < 2; ++kk)
        aB1[g][kk] = *(const bfrag*)(Bs + (bRow + 128 + g * 16) * 128 + ((kk * 64 + quad * 16) ^ rswz));
    __builtin_amdgcn_s_setprio(1);
#pragma unroll
    for (int f = 0; f < 4; ++f)
#pragma unroll
      for (int g = 0; g < 2; ++g)
#pragma unroll
        for (int kk = 0; kk < 2; ++kk)
          acc[0][f][1][g] = __builtin_amdgcn_mfma_f32_16x16x32_bf16(aA[f][kk], aB1[g][kk], acc[0][f][1][g], 0, 0, 0);
    __builtin_amdgcn_s_setprio(0);
    lds_barrier();

    // ---- phase 2: stage(t+2: B-h1); (mh1, nh1) ----
    if (pre) stageB(1, t + 2, Bs);
#pragma unroll
    for (int f = 0; f < 4; ++f)
#pragma unroll
      for (int kk = 0; kk < 2; ++kk)
        aA[f][kk] = *(const bfrag*)(As + (aRow + 128 + f * 16) * 128 + ((kk * 64 + quad * 16) ^ rswz));
    __builtin_amdgcn_s_setprio(1);
#pragma unroll
    for (int f = 0; f < 4; ++f)
#pragma unroll
      for (int g = 0; g < 2; ++g)
#pragma unroll
        for (int kk = 0; kk < 2; ++kk)
          acc[1][f][1][g] = __builtin_amdgcn_mfma_f32_16x16x32_bf16(aA[f][kk], aB1[g][kk], acc[1][f][1][g], 0, 0, 0);
    __builtin_amdgcn_s_setprio(0);
    lds_barrier();

    // ---- phase 3: stage(t+2: A-h1); (mh1, nh0) — register-only compute ----
    if (pre) stageA(1, t + 2, As);
    __builtin_amdgcn_s_setprio(1);
#pragma unroll
    for (int f = 0; f < 4; ++f)
#pragma unroll
      for (int g = 0; g < 2; ++g)
#pragma unroll
        for (int kk = 0; kk < 2; ++kk)
          acc[1][f][0][g] = __builtin_amdgcn_mfma_f32_16x16x32_bf16(aA[f][kk], aB0[g][kk], acc[1][f][0][g], 0, 0, 0);
    __builtin_amdgcn_s_setprio(0);
    if (pre)
      asm volatile("s_waitcnt vmcnt(8)" ::: "memory");   // tile t+1 landed
    else if (t + 1 < nt)
      asm volatile("s_waitcnt vmcnt(0)" ::: "memory");   // epilogue drain
    lds_barrier();
  }

  // epilogue: C/D layout col=lane&15, row=quad*4+reg (m89/m91 verified)
#pragma unroll
  for (int mh = 0; mh < 2; ++mh)
#pragma unroll
    for (int f = 0; f < 4; ++f)
#pragma unroll
      for (int nh = 0; nh < 2; ++nh)
#pragma unroll
        for (int g = 0; g < 2; ++g)
#pragma unroll
          for (int rr = 0; rr < 4; ++rr) {
            int row = m0 + wr * 64 + mh * 128 + f * 16 + quad * 4 + rr;
            int col = n0 + wc * 32 + nh * 128 + g * 16 + l15;
            float v = acc[mh][f][nh][g][rr];
            if constexpr (__is_same(OutT, float))
              C[(size_t)row * N + col] = v;
            else
              C[(size_t)row * N + col] = f2bf(v);
          }
}

// ---------------------------------------------------------------------------
// RoPE (interleaved pairs) + scatter into Q[b][h][s][d] (token order) and
// paged K/V caches [blk][kvh][off][d] honoring block_tables.
// ---------------------------------------------------------------------------
__global__ __launch_bounds__(256) void rope_scatter(const u16* __restrict__ xqkv,
                                                    const int* __restrict__ positions,
                                                    const int* __restrict__ btab,
                                                    u16* __restrict__ qb,
                                                    u16* __restrict__ kb,
                                                    u16* __restrict__ vbuf) {
  int t = blockIdx.x;
  int tid = threadIdx.x;
  int b = t >> 10, srow = t & 1023;
  int pos = positions[t];
  int blk = btab[b * (SEQ / BLKSZ) + (pos >> 4)];
  int off = pos & (BLKSZ - 1);
  int c0 = tid * 16;

  struct __align__(16) { uint4 a, bq; } vv, oo;
  const u16* src = xqkv + (size_t)t * 4096 + c0;
  vv.a  = *(const uint4*)src;
  vv.bq = *(const uint4*)(src + 8);
  const u16* v = (const u16*)&vv;
  u16* o = (u16*)&oo;

  if (c0 < 3072) {  // Q or K section: apply RoPE on (even,odd) pairs
    int dbase = c0 & 127;
    float fpos = (float)pos;
    for (int j = 0; j < 8; ++j) {
      int i = (dbase >> 1) + j;                       // freq index 0..63
      float inv = exp2f(-(float)i * (13.287712379549449f / 64.0f)); // 10000^(-i/64)
      float ang = fpos * inv;
      float sn, cs;
      sincosf(ang, &sn, &cs);
      float fr = bf2f(v[2 * j]), fi = bf2f(v[2 * j + 1]);
      o[2 * j]     = f2bf(fr * cs - fi * sn);
      o[2 * j + 1] = f2bf(fr * sn + fi * cs);
    }
  } else {
    for (int j = 0; j < 16; ++j) o[j] = v[j];
  }

  u16* dst;
  if (c0 < 2048) {
    int head = c0 >> 7, d0 = c0 & 127;
    dst = qb + (((size_t)(b * NH + head)) * SEQ + srow) * HD + d0;
  } else if (c0 < 3072) {
    int cc = c0 - 2048;
    int kvh = cc >> 7, d0 = cc & 127;
    dst = kb + (((size_t)(blk * NKV + kvh) * BLKSZ + off)) * HD + d0;
  } else {
    int cc = c0 - 3072;
    int kvh = cc >> 7, d0 = cc & 127;
    dst = vbuf + (((size_t)(blk * NKV + kvh) * BLKSZ + off)) * HD + d0;
  }
  *(uint4*)dst = oo.a;
  *(uint4*)(dst + 8) = oo.bq;
}

// ---------------------------------------------------------------------------
// Flash attention v2, paged cache — KVT=64 + T14 (round-4 verified: passed,
// attn below the gemm dispatches; unchanged).
// ---------------------------------------------------------------------------
#define KVT 64
#define KS_STRIDE 272   // bytes per K token row (128*2 + 16 pad)
#define VT_STRIDE 144   // bytes per V d row (64*2 + 16 pad)
#define PS_STRIDE 144   // bytes per P q row (64*2 + 16 pad)

__global__ __launch_bounds__(512) void attn_kernel(const u16* __restrict__ Q,
                                                   const u16* __restrict__ Kc,
                                                   const u16* __restrict__ Vc,
                                                   const int* __restrict__ positions,
                                                   const int* __restrict__ btab,
                                                   u16* __restrict__ O) {
  __shared__ __align__(16) u16 Ks[KVT * (KS_STRIDE / 2)];
  __shared__ __align__(16) u16 Vt[HD * (VT_STRIDE / 2)];
  __shared__ __align__(16) u16 Ps[8 * 16 * (PS_STRIDE / 2)];
  const float SM_SCALE = 0.08838834764831845f; // 1/sqrt(128)
  const float LOG2E    = 1.4426950408889634f;
  const float C1       = SM_SCALE * LOG2E;
  const float NEGBIG   = -30000.0f;
  const float NEGINIT  = -1e30f;
  const float DEFER2   = 8.0f * LOG2E;

  int tid = threadIdx.x;
  int wave = tid >> 6, lane = tid & 63, quad = lane >> 4, l15 = lane & 15;
  int bid = blockIdx.x;
  int bh = bid >> 2, pr = bid & 3;
  int b = bh >> 4, h = bh & 15, kvh = h >> 1;
  const int* btrow = btab + b * (SEQ / BLKSZ);

  char* KsB = (char*)Ks;
  char* VtB = (char*)Vt;
  char* myPsB = (char*)Ps + wave * 16 * PS_STRIDE;

  int tokA = tid >> 4;
  int tokB = tokA + 32;
  int dgK  = tid & 15;
  int tokV = (tid & 31) * 2;
  int vd0  = (tid >> 5) * 8;

  uint4 kr0, kr1, vr0, vr1;

  auto load_tile = [&](int kti) {
    int i0 = kti >> 4;
    int b0 = btrow[i0], b1 = btrow[i0 + 1], b2 = btrow[i0 + 2], b3 = btrow[i0 + 3];
    const u16* KA = Kc + ((size_t)(((tokA < 16) ? b0 : b1) * NKV + kvh) * BLKSZ + (tokA & 15)) * HD + dgK * 8;
    const u16* KB = Kc + ((size_t)(((tokB < 48) ? b2 : b3) * NKV + kvh) * BLKSZ + (tokB & 15)) * HD + dgK * 8;
    kr0 = *(const uint4*)KA;
    kr1 = *(const uint4*)KB;
    int bv = (tokV < 16) ? b0 : (tokV < 32) ? b1 : (tokV < 48) ? b2 : b3;
    const u16* VA = Vc + ((size_t)(bv * NKV + kvh) * BLKSZ + (tokV & 15)) * HD + vd0;
    vr0 = *(const uint4*)VA;
    vr1 = *(const uint4*)(VA + HD);
  };

  for (int pass = 0; pass < 2; ++pass) {
    int yt = pass ? (7 - pr) : pr;
    int q0 = yt * 128;
    int qw = q0 + wave * 16;

    const u16* Qbase = Q + ((size_t)bh * SEQ + qw) * HD;

    bfrag aq[4];
#pragma unroll
    for (int kb2 = 0; kb2 < 4; ++kb2)
      aq[kb2] = *(const bfrag*)(Qbase + (size_t)l15 * HD + kb2 * 32 + quad * 8);

    int qpos[4];
#pragma unroll
    for (int r = 0; r < 4; ++r)
      qpos[r] = positions[(size_t)b * SEQ + qw + quad * 4 + r];

    f32x4 oa[8];
#pragma unroll
    for (int jd = 0; jd < 8; ++jd) oa[jd] = (f32x4){0.f, 0.f, 0.f, 0.f};
    float m2_i[4], l_i[4];
#pragma unroll
    for (int r = 0; r < 4; ++r) { m2_i[r] = NEGINIT; l_i[r] = 0.f; }

    int kend = q0 + 128;
    load_tile(0);

    for (int kt = 0; kt < kend; kt += KVT) {
      __syncthreads();
      *(uint4*)(KsB + tokA * KS_STRIDE + dgK * 16) = kr0;
      *(uint4*)(KsB + tokB * KS_STRIDE + dgK * 16) = kr1;
      {
        const u16* p0 = (const u16*)&vr0;
        const u16* p1 = (const u16*)&vr1;
#pragma unroll
        for (int jj = 0; jj < 8; ++jj) {
          unsigned int val = (unsigned int)p0[jj] | ((unsigned int)p1[jj] << 16);
          *(unsigned int*)(VtB + (vd0 + jj) * VT_STRIDE + tokV * 2) = val;
        }
      }
      __syncthreads();

      if (kt + KVT < kend) load_tile(kt + KVT);

      if (kt <= qw + 15) {
        f32x4 sa[4];
#pragma unroll
        for (int jn = 0; jn < 4; ++jn) sa[jn] = (f32x4){0.f, 0.f, 0.f, 0.f};
#pragma unroll
        for (int kb2 = 0; kb2 < 4; ++kb2) {
#pragma unroll
          for (int jn = 0; jn < 4; ++jn) {
            bfrag bk = *(const bfrag*)(KsB + (jn * 16 + l15) * KS_STRIDE + (kb2 * 4 + quad) * 16);
            sa[jn] = __builtin_amdgcn_mfma_f32_16x16x32_bf16(aq[kb2], bk, sa[jn], 0, 0, 0);
          }
        }

        float m2x[4];
#pragma unroll
        for (int r = 0; r < 4; ++r) {
#pragma unroll
          for (int jn = 0; jn < 4; ++jn) {
            float s = sa[jn][r];
            if (kt + jn * 16 + l15 > qpos[r]) s = NEGBIG;
            sa[jn][r] = s;
          }
          float m0 = fmaxf(fmaxf(sa[0][r], sa[1][r]), fmaxf(sa[2][r], sa[3][r]));
          m0 = fmaxf(m0, __shfl_xor(m0, 1, 64));
          m0 = fmaxf(m0, __shfl_xor(m0, 2, 64));
          m0 = fmaxf(m0, __shfl_xor(m0, 4, 64));
          m0 = fmaxf(m0, __shfl_xor(m0, 8, 64));
          m2x[r] = m0 * C1;
        }

        bool ok = (m2x[0] <= m2_i[0] + DEFER2) && (m2x[1] <= m2_i[1] + DEFER2) &&
                  (m2x[2] <= m2_i[2] + DEFER2) && (m2x[3] <= m2_i[3] + DEFER2);
        if (__all(ok)) {
#pragma unroll
          for (int r = 0; r < 4; ++r) {
            float rs = 0.f;
#pragma unroll
            for (int jn = 0; jn < 4; ++jn) {
              float pv = exp2f(sa[jn][r] * C1 - m2_i[r]);
              sa[jn][r] = pv;
              rs += pv;
            }
            rs += __shfl_xor(rs, 1, 64);
            rs += __shfl_xor(rs, 2, 64);
            rs += __shfl_xor(rs, 4, 64);
            rs += __shfl_xor(rs, 8, 64);
            l_i[r] += rs;
          }
        } else {
          float alpha[4];
#pragma unroll
          for (int r = 0; r < 4; ++r) {
            float m2n = fmaxf(m2_i[r], m2x[r]);
            float al = exp2f(m2_i[r] - m2n);
            float rs = 0.f;
#pragma unroll
            for (int jn = 0; jn < 4; ++jn) {
              float pv = exp2f(sa[jn][r] * C1 - m2n);
              sa[jn][r] = pv;
              rs += pv;
            }
            rs += __shfl_xor(rs, 1, 64);
            rs += __shfl_xor(rs, 2, 64);
            rs += __shfl_xor(rs, 4, 64);
            rs += __shfl_xor(rs, 8, 64);
            l_i[r] = l_i[r] * al + rs;
            m2_i[r] = m2n;
            alpha[r] = al;
          }
#pragma unroll
          for (int jd = 0; jd < 8; ++jd) {
            oa[jd][0] *= alpha[0];
            oa[jd][1] *= alpha[1];
            oa[jd][2] *= alpha[2];
            oa[jd][3] *= alpha[3];
          }
        }

#pragma unroll
        for (int r = 0; r < 4; ++r) {
          int q = quad * 4 + r;
#pragma unroll
          for (int jn = 0; jn < 4; ++jn)
            *(u16*)(myPsB + q * PS_STRIDE + (jn * 16 + l15) * 2) = f2bf(sa[jn][r]);
        }
        bfrag ap0 = *(const bfrag*)(myPsB + l15 * PS_STRIDE + quad * 16);
        bfrag ap1 = *(const bfrag*)(myPsB + l15 * PS_STRIDE + 64 + quad * 16);
#pragma unroll
        for (int jd = 0; jd < 8; ++jd) {
          int d = jd * 16 + l15;
          bfrag bv0 = *(const bfrag*)(VtB + d * VT_STRIDE + quad * 16);
          bfrag bv1 = *(const bfrag*)(VtB + d * VT_STRIDE + 64 + quad * 16);
          oa[jd] = __builtin_amdgcn_mfma_f32_16x16x32_bf16(ap0, bv0, oa[jd], 0, 0, 0);
          oa[jd] = __builtin_amdgcn_mfma_f32_16x16x32_bf16(ap1, bv1, oa[jd], 0, 0, 0);
        }
      }
    }

#pragma unroll
    for (int r = 0; r < 4; ++r) {
      float inv = 1.0f / fmaxf(l_i[r], 1e-30f);
      size_t trow = (size_t)b * SEQ + qw + quad * 4 + r;
#pragma unroll
      for (int jd = 0; jd < 8; ++jd)
        O[trow * 2048 + (size_t)h * HD + jd * 16 + l15] = f2bf(oa[jd][r] * inv);
    }
  }
}

// ---------------------------------------------------------------------------
extern "C" void kernel_launch(void* const* d_in, const int* in_sizes, int n_in,
                              void* d_out, int out_size, void* d_ws, size_t ws_size,
                              hipStream_t stream) {
  (void)in_sizes; (void)n_in; (void)out_size;
  const float* xf  = (const float*)d_in[0];
  const float* wqf = (const float*)d_in[1];
  const float* wkf = (const float*)d_in[2];
  const float* wvf = (const float*)d_in[3];
  const float* wof = (const float*)d_in[4];
  const int* positions = (const int*)d_in[7];
  const int* btab      = (const int*)d_in[10];
  float* out = (float*)d_out;

  u16* ws    = (u16*)d_ws;
  u16* woT   = ws;                                  // [2048][2048]
  u16* wqkvT = woT + (size_t)2048 * 2048;           // [4096][2048]
  u16* xbf   = wqkvT + (size_t)4096 * 2048;         // [8192][2048]
  u16* xqkv  = xbf + (size_t)8192 * 2048;           // [8192][4096]
  u16* qb    = xqkv + (size_t)8192 * 4096;          // [8][16][1024][128]
  u16* kbuf  = qb + (size_t)8192 * 2048;            // paged K
  u16* vbuf  = kbuf + (size_t)8192 * 1024;          // paged V
  u16* wsend = vbuf + (size_t)8192 * 1024;

  size_t base_elems = (size_t)(wsend - ws);
  size_t obuf_elems = (size_t)8192 * 2048;
  u16* obuf;
  if (ws_size >= (base_elems + obuf_elems) * sizeof(u16))
    obuf = wsend;
  else
    obuf = wqkvT;

  if (ws_size < base_elems * sizeof(u16)) return;

  f32_to_bf16<<<dim3(8192), 256, 0, stream>>>(xf, xbf, (size_t)8192 * 2048);
  ktranspose_f<<<dim3(32, 32), 256, 0, stream>>>(wqf, wqkvT, 2048, 2048);
  ktranspose_f<<<dim3(16, 32), 256, 0, stream>>>(wkf, wqkvT + (size_t)2048 * 2048, 2048, 1024);
  ktranspose_f<<<dim3(16, 32), 256, 0, stream>>>(wvf, wqkvT + (size_t)3072 * 2048, 2048, 1024);
  ktranspose_f<<<dim3(32, 32), 256, 0, stream>>>(wof, woT, 2048, 2048);
  // QKV projection: 256x256 8-wave phase-interleaved GEMM (512 blocks, %8==0)
  gemm_bt8<u16><<<dim3(16, 32), 512, 0, stream>>>(xbf, wqkvT, xqkv, 8192, 4096, 2048);
  rope_scatter<<<dim3(8192), 256, 0, stream>>>(xqkv, positions, btab, qb, kbuf, vbuf);
  attn_kernel<<<dim3(512), 512, 0, stream>>>(qb, kbuf, vbuf, positions, btab, obuf);
  // output projection (256 blocks, %8==0)
  gemm_bt8<float><<<dim3(8, 32), 512, 0, stream>>>(obuf, woT, out, 8192, 2048, 2048);
}

// Round 7
// 533.667 us; speedup vs baseline: 1.4009x; 1.0511x over previous
//
#include <hip/hip_runtime.h>
#include <stdint.h>

// Problem constants (Attention_39556648796173)
#define TTOK  8192
#define DIMM  2048
#define NH    16
#define NKV   8
#define HD    128
#define SEQ   1024
#define BATCH 8
#define BLKSZ 16

typedef unsigned short u16;
typedef __attribute__((ext_vector_type(8))) short bfrag;   // 8 x bf16 (4 VGPRs)
typedef __attribute__((ext_vector_type(4))) float f32x4;   // MFMA accumulator

__device__ __forceinline__ float bf2f(u16 u) {
  unsigned int v = ((unsigned int)u) << 16;
  float f; __builtin_memcpy(&f, &v, 4); return f;
}
__device__ __forceinline__ u16 f2bf(float f) {
  unsigned int v; __builtin_memcpy(&v, &f, 4);
  v = v + 0x7FFFu + ((v >> 16) & 1u);   // RNE
  return (u16)(v >> 16);
}

// async global->LDS, 16B per lane; LDS dest = wave-uniform base + lane*16
__device__ __forceinline__ void gll16(const void* g, void* l) {
  __builtin_amdgcn_global_load_lds(
      (__attribute__((address_space(1))) void*)(g),
      (__attribute__((address_space(3))) void*)(l), 16, 0, 0);
}

// ---------------------------------------------------------------------------
// fp32 -> bf16 bulk convert (n multiple of 2048); 8 elems/thread
// ---------------------------------------------------------------------------
__global__ __launch_bounds__(256) void f32_to_bf16(const float* __restrict__ in,
                                                   u16* __restrict__ out, size_t n) {
  size_t i = ((size_t)blockIdx.x * 256 + threadIdx.x) * 8;
  if (i >= n) return;
  float4 a = *(const float4*)(in + i);
  float4 b = *(const float4*)(in + i + 4);
  union { u16 o[8]; uint4 v; } u;
  u.o[0] = f2bf(a.x); u.o[1] = f2bf(a.y); u.o[2] = f2bf(a.z); u.o[3] = f2bf(a.w);
  u.o[4] = f2bf(b.x); u.o[5] = f2bf(b.y); u.o[6] = f2bf(b.z); u.o[7] = f2bf(b.w);
  *(uint4*)(out + i) = u.v;
}

// ---------------------------------------------------------------------------
// Tiled transpose + fp32->bf16: out[n][k] = bf16(in[k][n]), K,N multiples of 64
// ---------------------------------------------------------------------------
__global__ __launch_bounds__(256) void ktranspose_f(const float* __restrict__ in,
                                                    u16* __restrict__ out, int K, int N) {
  __shared__ __align__(16) u16 tile[64 * 65];
  int n0 = blockIdx.x * 64, k0 = blockIdx.y * 64;
  int tx = threadIdx.x & 63, ty = threadIdx.x >> 6;
  for (int r = 0; r < 16; ++r) {
    int kk = r * 4 + ty;
    tile[kk * 65 + tx] = f2bf(in[(size_t)(k0 + kk) * N + n0 + tx]);
  }
  __syncthreads();
  for (int r = 0; r < 16; ++r) {
    int nn = r * 4 + ty;
    out[(size_t)(n0 + nn) * K + k0 + tx] = tile[tx * 65 + nn];
  }
}

// ---------------------------------------------------------------------------
// 256x256 ring-buffered GEMM: C[M,N] = A[M,K] @ Bt[N,K]^T.
// BK=32, 4-buffer LDS ring (4 x 16KB x {A,B} = 128 KiB), 8 waves (2Mx4N),
// per-wave 128x64 output, mfma 16x16x32 bf16, 1 block/CU.
//
// Round-6 post-mortem: the 4-phase schedule was LDS-issue-bound (96
// ds_read_b128/tile/CU ~ 1150-2300cy vs 155cy MFMA issue) and paid 4
// lgkm-drained barriers + sched_barriers per tile (~5.9k cy/tile measured).
// This version: ONE barrier per tile, no phases. Staging tile t+3 targets
// buf[(t+3)&3], whose reads finished before the END-OF-(t-1) barrier -> no
// intra-tile hazard exists; compiler freely interleaves reads/stage/MFMA.
//
// Ledger (per wave, 4 gll16 per stage):
//   prologue: stage(0,1,2) -> 12 outstanding; vmcnt(8) -> tile0 landed; barrier
//   tile t:   12 ds_read (buf t&3) + stage(t+3 -> buf t&3... (t+3)&3) + 32 MFMA
//             lgkmcnt(0); sched_barrier(0)        // reads done pre-barrier
//             vmcnt(8)  -> retires t+1 (oldest 4 of {t+1,t+2,t+3}=12)  [T4]
//             s_barrier                            // ONE per tile
//   buffer reuse: buf[t&3] next written by stage(t+4) in iter t+1 — after
//   this barrier, all waves' t-reads have drained. Safe.
//
// Swizzle (T2, rule 21 involution, 64B rows): LDS slot s of row r holds
// global 16B-slot s ^ (r&3). gll16 source pre-applies it; frag reads use
// slot quad ^ (l15&3). Verified uniform 8 touches/bank = b128 floor.
// ---------------------------------------------------------------------------
template <typename OutT>
__global__ __launch_bounds__(512, 2) void gemm_bt4(const u16* __restrict__ A,
                                                   const u16* __restrict__ Bt,
                                                   OutT* __restrict__ C,
                                                   int M, int N, int K) {
  __shared__ __align__(16) u16 AS[4][256 * 32];   // 16KB per buffer
  __shared__ __align__(16) u16 BS[4][256 * 32];
  (void)M;
  int tid = threadIdx.x;
  int w = tid >> 6, lane = tid & 63, quad = lane >> 4, l15 = lane & 15;
  int wr = w >> 2, wc = w & 3;          // 2 M-warps x 4 N-warps

  // XCD-bijective block swizzle (grid counts are multiples of 8 here)
  int nwg = gridDim.x * gridDim.y;
  int id = blockIdx.y * gridDim.x + blockIdx.x;
  int swz = (id & 7) * (nwg >> 3) + (id >> 3);
  int bx = swz % gridDim.x, by = swz / gridDim.x;
  int m0 = by * 256, n0 = bx * 256;

  size_t Kb = (size_t)K * 2;            // bytes per row
  int nt = K >> 5;                      // K-tiles of 32

  // staging decode: wave w stages rows [w*32, w*32+32) of A and Bt.
  // load r (0,1): rows w*32 + r*16 + (lane>>2); LDS linear slot index
  // (w*2+r)*64 + lane  ->  row = idx>>2, slot = lane&3.
  // Pre-swizzled source slot = (lane&3) ^ ((lane>>2)&3)   [row&3 == (lane>>2)&3]
  int srow = w * 32 + (lane >> 2);
  int gslot = ((lane & 3) ^ ((lane >> 2) & 3)) * 16;
  auto stage = [&](int tk) {
    int bsel = tk & 3;
    char* Ad = (char*)AS[bsel] + (w * 2) * 1024 + lane * 16;
    char* Bd = (char*)BS[bsel] + (w * 2) * 1024 + lane * 16;
    const char* As0 = (const char*)A + (size_t)(m0 + srow) * Kb + (size_t)tk * 64 + gslot;
    const char* Bs0 = (const char*)Bt + (size_t)(n0 + srow) * Kb + (size_t)tk * 64 + gslot;
    gll16(As0, Ad);
    gll16(As0 + 16 * Kb, Ad + 1024);
    gll16(Bs0, Bd);
    gll16(Bs0 + 16 * Kb, Bd + 1024);
  };

  f32x4 acc[2][4][2][2];                // [mh][f][nh][g]
#pragma unroll
  for (int mh = 0; mh < 2; ++mh)
#pragma unroll
    for (int f = 0; f < 4; ++f)
#pragma unroll
      for (int nh = 0; nh < 2; ++nh)
#pragma unroll
        for (int g = 0; g < 2; ++g) acc[mh][f][nh][g] = (f32x4){0.f, 0.f, 0.f, 0.f};

  // prologue: stage tiles 0,1,2 (12 loads out); tile 0 landed; barrier.
  stage(0); stage(1); stage(2);
  asm volatile("s_waitcnt vmcnt(8)" ::: "memory");
  __builtin_amdgcn_s_barrier();

  int rdoff = ((quad ^ (l15 & 3)) << 4);          // swizzled slot byte
  int aRowB = (wr * 64 + l15) * 64 + rdoff;       // + (mh*128 + f*16)*64
  int bRowB = (wc * 32 + l15) * 64 + rdoff;       // + (nh*128 + g*16)*64

  for (int t = 0; t < nt; ++t) {
    const char* Ab = (const char*)AS[t & 3];
    const char* Bb = (const char*)BS[t & 3];

    bfrag aA[2][4], bB[2][2];
#pragma unroll
    for (int mh = 0; mh < 2; ++mh)
#pragma unroll
      for (int f = 0; f < 4; ++f)
        aA[mh][f] = *(const bfrag*)(Ab + aRowB + (mh * 128 + f * 16) * 64);
#pragma unroll
    for (int nh = 0; nh < 2; ++nh)
#pragma unroll
      for (int g = 0; g < 2; ++g)
        bB[nh][g] = *(const bfrag*)(Bb + bRowB + (nh * 128 + g * 16) * 64);

    if (t + 3 < nt) stage(t + 3);       // into buf[(t+3)&3] (safe: see header)

    __builtin_amdgcn_s_setprio(1);
#pragma unroll
    for (int mh = 0; mh < 2; ++mh)
#pragma unroll
      for (int f = 0; f < 4; ++f)
#pragma unroll
        for (int nh = 0; nh < 2; ++nh)
#pragma unroll
          for (int g = 0; g < 2; ++g)
            acc[mh][f][nh][g] = __builtin_amdgcn_mfma_f32_16x16x32_bf16(
                aA[mh][f], bB[nh][g], acc[mh][f][nh][g], 0, 0, 0);
    __builtin_amdgcn_s_setprio(0);

    asm volatile("s_waitcnt lgkmcnt(0)" ::: "memory");  // own reads drained
    __builtin_amdgcn_sched_barrier(0);                  // rule-18 insurance
    if (t + 3 < nt)
      asm volatile("s_waitcnt vmcnt(8)" ::: "memory");  // t+1 landed (counted)
    else if (t + 1 < nt)
      asm volatile("s_waitcnt vmcnt(0)" ::: "memory");  // epilogue drain
    __builtin_amdgcn_s_barrier();                       // ONE barrier per tile
  }

  // epilogue: C/D layout col=lane&15, row=quad*4+reg (m89/m91 verified)
#pragma unroll
  for (int mh = 0; mh < 2; ++mh)
#pragma unroll
    for (int f = 0; f < 4; ++f)
#pragma unroll
      for (int nh = 0; nh < 2; ++nh)
#pragma unroll
        for (int g = 0; g < 2; ++g)
#pragma unroll
          for (int rr = 0; rr < 4; ++rr) {
            int row = m0 + wr * 64 + mh * 128 + f * 16 + quad * 4 + rr;
            int col = n0 + wc * 32 + nh * 128 + g * 16 + l15;
            float v = acc[mh][f][nh][g][rr];
            if constexpr (__is_same(OutT, float))
              C[(size_t)row * N + col] = v;
            else
              C[(size_t)row * N + col] = f2bf(v);
          }
}

// ---------------------------------------------------------------------------
// RoPE (interleaved pairs) + scatter into Q[b][h][s][d] (token order) and
// paged K/V caches [blk][kvh][off][d] honoring block_tables.
// ---------------------------------------------------------------------------
__global__ __launch_bounds__(256) void rope_scatter(const u16* __restrict__ xqkv,
                                                    const int* __restrict__ positions,
                                                    const int* __restrict__ btab,
                                                    u16* __restrict__ qb,
                                                    u16* __restrict__ kb,
                                                    u16* __restrict__ vbuf) {
  int t = blockIdx.x;
  int tid = threadIdx.x;
  int b = t >> 10, srow = t & 1023;
  int pos = positions[t];
  int blk = btab[b * (SEQ / BLKSZ) + (pos >> 4)];
  int off = pos & (BLKSZ - 1);
  int c0 = tid * 16;

  struct __align__(16) { uint4 a, bq; } vv, oo;
  const u16* src = xqkv + (size_t)t * 4096 + c0;
  vv.a  = *(const uint4*)src;
  vv.bq = *(const uint4*)(src + 8);
  const u16* v = (const u16*)&vv;
  u16* o = (u16*)&oo;

  if (c0 < 3072) {  // Q or K section: apply RoPE on (even,odd) pairs
    int dbase = c0 & 127;
    float fpos = (float)pos;
    for (int j = 0; j < 8; ++j) {
      int i = (dbase >> 1) + j;                       // freq index 0..63
      float inv = exp2f(-(float)i * (13.287712379549449f / 64.0f)); // 10000^(-i/64)
      float ang = fpos * inv;
      float sn, cs;
      sincosf(ang, &sn, &cs);
      float fr = bf2f(v[2 * j]), fi = bf2f(v[2 * j + 1]);
      o[2 * j]     = f2bf(fr * cs - fi * sn);
      o[2 * j + 1] = f2bf(fr * sn + fi * cs);
    }
  } else {
    for (int j = 0; j < 16; ++j) o[j] = v[j];
  }

  u16* dst;
  if (c0 < 2048) {
    int head = c0 >> 7, d0 = c0 & 127;
    dst = qb + (((size_t)(b * NH + head)) * SEQ + srow) * HD + d0;
  } else if (c0 < 3072) {
    int cc = c0 - 2048;
    int kvh = cc >> 7, d0 = cc & 127;
    dst = kb + (((size_t)(blk * NKV + kvh) * BLKSZ + off)) * HD + d0;
  } else {
    int cc = c0 - 3072;
    int kvh = cc >> 7, d0 = cc & 127;
    dst = vbuf + (((size_t)(blk * NKV + kvh) * BLKSZ + off)) * HD + d0;
  }
  *(uint4*)dst = oo.a;
  *(uint4*)(dst + 8) = oo.bq;
}

// ---------------------------------------------------------------------------
// Flash attention v2, paged cache — KVT=64 + T14 (verified rounds 4/6;
// unchanged).
// ---------------------------------------------------------------------------
#define KVT 64
#define KS_STRIDE 272   // bytes per K token row (128*2 + 16 pad)
#define VT_STRIDE 144   // bytes per V d row (64*2 + 16 pad)
#define PS_STRIDE 144   // bytes per P q row (64*2 + 16 pad)

__global__ __launch_bounds__(512) void attn_kernel(const u16* __restrict__ Q,
                                                   const u16* __restrict__ Kc,
                                                   const u16* __restrict__ Vc,
                                                   const int* __restrict__ positions,
                                                   const int* __restrict__ btab,
                                                   u16* __restrict__ O) {
  __shared__ __align__(16) u16 Ks[KVT * (KS_STRIDE / 2)];
  __shared__ __align__(16) u16 Vt[HD * (VT_STRIDE / 2)];
  __shared__ __align__(16) u16 Ps[8 * 16 * (PS_STRIDE / 2)];
  const float SM_SCALE = 0.08838834764831845f; // 1/sqrt(128)
  const float LOG2E    = 1.4426950408889634f;
  const float C1       = SM_SCALE * LOG2E;
  const float NEGBIG   = -30000.0f;
  const float NEGINIT  = -1e30f;
  const float DEFER2   = 8.0f * LOG2E;

  int tid = threadIdx.x;
  int wave = tid >> 6, lane = tid & 63, quad = lane >> 4, l15 = lane & 15;
  int bid = blockIdx.x;
  int bh = bid >> 2, pr = bid & 3;
  int b = bh >> 4, h = bh & 15, kvh = h >> 1;
  const int* btrow = btab + b * (SEQ / BLKSZ);

  char* KsB = (char*)Ks;
  char* VtB = (char*)Vt;
  char* myPsB = (char*)Ps + wave * 16 * PS_STRIDE;

  int tokA = tid >> 4;
  int tokB = tokA + 32;
  int dgK  = tid & 15;
  int tokV = (tid & 31) * 2;
  int vd0  = (tid >> 5) * 8;

  uint4 kr0, kr1, vr0, vr1;

  auto load_tile = [&](int kti) {
    int i0 = kti >> 4;
    int b0 = btrow[i0], b1 = btrow[i0 + 1], b2 = btrow[i0 + 2], b3 = btrow[i0 + 3];
    const u16* KA = Kc + ((size_t)(((tokA < 16) ? b0 : b1) * NKV + kvh) * BLKSZ + (tokA & 15)) * HD + dgK * 8;
    const u16* KB = Kc + ((size_t)(((tokB < 48) ? b2 : b3) * NKV + kvh) * BLKSZ + (tokB & 15)) * HD + dgK * 8;
    kr0 = *(const uint4*)KA;
    kr1 = *(const uint4*)KB;
    int bv = (tokV < 16) ? b0 : (tokV < 32) ? b1 : (tokV < 48) ? b2 : b3;
    const u16* VA = Vc + ((size_t)(bv * NKV + kvh) * BLKSZ + (tokV & 15)) * HD + vd0;
    vr0 = *(const uint4*)VA;
    vr1 = *(const uint4*)(VA + HD);
  };

  for (int pass = 0; pass < 2; ++pass) {
    int yt = pass ? (7 - pr) : pr;
    int q0 = yt * 128;
    int qw = q0 + wave * 16;

    const u16* Qbase = Q + ((size_t)bh * SEQ + qw) * HD;

    bfrag aq[4];
#pragma unroll
    for (int kb2 = 0; kb2 < 4; ++kb2)
      aq[kb2] = *(const bfrag*)(Qbase + (size_t)l15 * HD + kb2 * 32 + quad * 8);

    int qpos[4];
#pragma unroll
    for (int r = 0; r < 4; ++r)
      qpos[r] = positions[(size_t)b * SEQ + qw + quad * 4 + r];

    f32x4 oa[8];
#pragma unroll
    for (int jd = 0; jd < 8; ++jd) oa[jd] = (f32x4){0.f, 0.f, 0.f, 0.f};
    float m2_i[4], l_i[4];
#pragma unroll
    for (int r = 0; r < 4; ++r) { m2_i[r] = NEGINIT; l_i[r] = 0.f; }

    int kend = q0 + 128;
    load_tile(0);

    for (int kt = 0; kt < kend; kt += KVT) {
      __syncthreads();
      *(uint4*)(KsB + tokA * KS_STRIDE + dgK * 16) = kr0;
      *(uint4*)(KsB + tokB * KS_STRIDE + dgK * 16) = kr1;
      {
        const u16* p0 = (const u16*)&vr0;
        const u16* p1 = (const u16*)&vr1;
#pragma unroll
        for (int jj = 0; jj < 8; ++jj) {
          unsigned int val = (unsigned int)p0[jj] | ((unsigned int)p1[jj] << 16);
          *(unsigned int*)(VtB + (vd0 + jj) * VT_STRIDE + tokV * 2) = val;
        }
      }
      __syncthreads();

      if (kt + KVT < kend) load_tile(kt + KVT);

      if (kt <= qw + 15) {
        f32x4 sa[4];
#pragma unroll
        for (int jn = 0; jn < 4; ++jn) sa[jn] = (f32x4){0.f, 0.f, 0.f, 0.f};
#pragma unroll
        for (int kb2 = 0; kb2 < 4; ++kb2) {
#pragma unroll
          for (int jn = 0; jn < 4; ++jn) {
            bfrag bk = *(const bfrag*)(KsB + (jn * 16 + l15) * KS_STRIDE + (kb2 * 4 + quad) * 16);
            sa[jn] = __builtin_amdgcn_mfma_f32_16x16x32_bf16(aq[kb2], bk, sa[jn], 0, 0, 0);
          }
        }

        float m2x[4];
#pragma unroll
        for (int r = 0; r < 4; ++r) {
#pragma unroll
          for (int jn = 0; jn < 4; ++jn) {
            float s = sa[jn][r];
            if (kt + jn * 16 + l15 > qpos[r]) s = NEGBIG;
            sa[jn][r] = s;
          }
          float m0 = fmaxf(fmaxf(sa[0][r], sa[1][r]), fmaxf(sa[2][r], sa[3][r]));
          m0 = fmaxf(m0, __shfl_xor(m0, 1, 64));
          m0 = fmaxf(m0, __shfl_xor(m0, 2, 64));
          m0 = fmaxf(m0, __shfl_xor(m0, 4, 64));
          m0 = fmaxf(m0, __shfl_xor(m0, 8, 64));
          m2x[r] = m0 * C1;
        }

        bool ok = (m2x[0] <= m2_i[0] + DEFER2) && (m2x[1] <= m2_i[1] + DEFER2) &&
                  (m2x[2] <= m2_i[2] + DEFER2) && (m2x[3] <= m2_i[3] + DEFER2);
        if (__all(ok)) {
#pragma unroll
          for (int r = 0; r < 4; ++r) {
            float rs = 0.f;
#pragma unroll
            for (int jn = 0; jn < 4; ++jn) {
              float pv = exp2f(sa[jn][r] * C1 - m2_i[r]);
              sa[jn][r] = pv;
              rs += pv;
            }
            rs += __shfl_xor(rs, 1, 64);
            rs += __shfl_xor(rs, 2, 64);
            rs += __shfl_xor(rs, 4, 64);
            rs += __shfl_xor(rs, 8, 64);
            l_i[r] += rs;
          }
        } else {
          float alpha[4];
#pragma unroll
          for (int r = 0; r < 4; ++r) {
            float m2n = fmaxf(m2_i[r], m2x[r]);
            float al = exp2f(m2_i[r] - m2n);
            float rs = 0.f;
#pragma unroll
            for (int jn = 0; jn < 4; ++jn) {
              float pv = exp2f(sa[jn][r] * C1 - m2n);
              sa[jn][r] = pv;
              rs += pv;
            }
            rs += __shfl_xor(rs, 1, 64);
            rs += __shfl_xor(rs, 2, 64);
            rs += __shfl_xor(rs, 4, 64);
            rs += __shfl_xor(rs, 8, 64);
            l_i[r] = l_i[r] * al + rs;
            m2_i[r] = m2n;
            alpha[r] = al;
          }
#pragma unroll
          for (int jd = 0; jd < 8; ++jd) {
            oa[jd][0] *= alpha[0];
            oa[jd][1] *= alpha[1];
            oa[jd][2] *= alpha[2];
            oa[jd][3] *= alpha[3];
          }
        }

#pragma unroll
        for (int r = 0; r < 4; ++r) {
          int q = quad * 4 + r;
#pragma unroll
          for (int jn = 0; jn < 4; ++jn)
            *(u16*)(myPsB + q * PS_STRIDE + (jn * 16 + l15) * 2) = f2bf(sa[jn][r]);
        }
        bfrag ap0 = *(const bfrag*)(myPsB + l15 * PS_STRIDE + quad * 16);
        bfrag ap1 = *(const bfrag*)(myPsB + l15 * PS_STRIDE + 64 + quad * 16);
#pragma unroll
        for (int jd = 0; jd < 8; ++jd) {
          int d = jd * 16 + l15;
          bfrag bv0 = *(const bfrag*)(VtB + d * VT_STRIDE + quad * 16);
          bfrag bv1 = *(const bfrag*)(VtB + d * VT_STRIDE + 64 + quad * 16);
          oa[jd] = __builtin_amdgcn_mfma_f32_16x16x32_bf16(ap0, bv0, oa[jd], 0, 0, 0);
          oa[jd] = __builtin_amdgcn_mfma_f32_16x16x32_bf16(ap1, bv1, oa[jd], 0, 0, 0);
        }
      }
    }

#pragma unroll
    for (int r = 0; r < 4; ++r) {
      float inv = 1.0f / fmaxf(l_i[r], 1e-30f);
      size_t trow = (size_t)b * SEQ + qw + quad * 4 + r;
#pragma unroll
      for (int jd = 0; jd < 8; ++jd)
        O[trow * 2048 + (size_t)h * HD + jd * 16 + l15] = f2bf(oa[jd][r] * inv);
    }
  }
}

// ---------------------------------------------------------------------------
extern "C" void kernel_launch(void* const* d_in, const int* in_sizes, int n_in,
                              void* d_out, int out_size, void* d_ws, size_t ws_size,
                              hipStream_t stream) {
  (void)in_sizes; (void)n_in; (void)out_size;
  const float* xf  = (const float*)d_in[0];
  const float* wqf = (const float*)d_in[1];
  const float* wkf = (const float*)d_in[2];
  const float* wvf = (const float*)d_in[3];
  const float* wof = (const float*)d_in[4];
  const int* positions = (const int*)d_in[7];
  const int* btab      = (const int*)d_in[10];
  float* out = (float*)d_out;

  u16* ws    = (u16*)d_ws;
  u16* woT   = ws;                                  // [2048][2048]
  u16* wqkvT = woT + (size_t)2048 * 2048;           // [4096][2048]
  u16* xbf   = wqkvT + (size_t)4096 * 2048;         // [8192][2048]
  u16* xqkv  = xbf + (size_t)8192 * 2048;           // [8192][4096]
  u16* qb    = xqkv + (size_t)8192 * 4096;          // [8][16][1024][128]
  u16* kbuf  = qb + (size_t)8192 * 2048;            // paged K
  u16* vbuf  = kbuf + (size_t)8192 * 1024;          // paged V
  u16* wsend = vbuf + (size_t)8192 * 1024;

  size_t base_elems = (size_t)(wsend - ws);
  size_t obuf_elems = (size_t)8192 * 2048;
  u16* obuf;
  if (ws_size >= (base_elems + obuf_elems) * sizeof(u16))
    obuf = wsend;
  else
    obuf = wqkvT;

  if (ws_size < base_elems * sizeof(u16)) return;

  f32_to_bf16<<<dim3(8192), 256, 0, stream>>>(xf, xbf, (size_t)8192 * 2048);
  ktranspose_f<<<dim3(32, 32), 256, 0, stream>>>(wqf, wqkvT, 2048, 2048);
  ktranspose_f<<<dim3(16, 32), 256, 0, stream>>>(wkf, wqkvT + (size_t)2048 * 2048, 2048, 1024);
  ktranspose_f<<<dim3(16, 32), 256, 0, stream>>>(wvf, wqkvT + (size_t)3072 * 2048, 2048, 1024);
  ktranspose_f<<<dim3(32, 32), 256, 0, stream>>>(wof, woT, 2048, 2048);
  // QKV projection: 256x256 ring-buffered GEMM (512 blocks, %8==0)
  gemm_bt4<u16><<<dim3(16, 32), 512, 0, stream>>>(xbf, wqkvT, xqkv, 8192, 4096, 2048);
  rope_scatter<<<dim3(8192), 256, 0, stream>>>(xqkv, positions, btab, qb, kbuf, vbuf);
  attn_kernel<<<dim3(512), 512, 0, stream>>>(qb, kbuf, vbuf, positions, btab, obuf);
  // output projection (256 blocks, %8==0)
  gemm_bt4<float><<<dim3(8, 32), 512, 0, stream>>>(obuf, woT, out, 8192, 2048, 2048);
}